// Round 2
// baseline (1186.427 us; speedup 1.0000x reference)
//
#include <hip/hip_runtime.h>
#include <hip/hip_bf16.h>
#include <math.h>

#define DIN 20
#define C 128
#define HC 256

// ---------------- K1: BN stats (second moment 20x20 + column sums) ----------------
__global__ __launch_bounds__(256) void k_stats(const float* __restrict__ x, int NR,
                                               float* __restrict__ stats)
// stats[0..399] = M (full 20x20), stats[400..419] = colsum
{
    __shared__ float L[256][DIN]; // 20 KB
    int t = threadIdx.x;
    int r = blockIdx.x * 256 + t;
    if (r < NR) {
        #pragma unroll
        for (int k = 0; k < DIN; k++) L[t][k] = x[r * DIN + k];
    } else {
        #pragma unroll
        for (int k = 0; k < DIN; k++) L[t][k] = 0.f;
    }
    __syncthreads();
    if (t < 210) {
        int p = 0, q = t;
        while (q >= DIN - p) { q -= (DIN - p); p++; }
        q += p;
        float acc = 0.f;
        for (int rr = 0; rr < 256; rr++) acc += L[rr][p] * L[rr][q];
        atomicAdd(&stats[p * DIN + q], acc);
        if (p != q) atomicAdd(&stats[q * DIN + p], acc);
    } else if (t < 230) {
        int k = t - 210;
        float acc = 0.f;
        for (int rr = 0; rr < 256; rr++) acc += L[rr][k];
        atomicAdd(&stats[400 + k], acc);
    }
}

// ---------------- K2: fold BN into scale/shift; precompute v_d = w_d @ att_d ------
__global__ __launch_bounds__(256) void k_precomp(float* __restrict__ stats,
    const float* __restrict__ W, const float* __restrict__ b,
    const float* __restrict__ gamma, const float* __restrict__ beta,
    const float* __restrict__ g1_wd, const float* __restrict__ g1_ad,
    const float* __restrict__ g2_wd, const float* __restrict__ g2_ad, float invN)
// writes stats[420..547]=s, [548..675]=tsh, [676..931]=vd1[k*2+h], [932..1187]=vd2
{
    int t = threadIdx.x;
    if (t < C) {
        float w[DIN];
        #pragma unroll
        for (int k = 0; k < DIN; k++) w[k] = W[k * C + t];
        float mb = 0.f;
        #pragma unroll
        for (int k = 0; k < DIN; k++) mb += stats[400 + k] * invN * w[k];
        float e2 = 0.f;
        for (int p = 0; p < DIN; p++) {
            float acc2 = 0.f;
            for (int q = 0; q < DIN; q++) acc2 += stats[p * DIN + q] * w[q];
            e2 += w[p] * acc2;
        }
        e2 *= invN;
        float var = e2 - mb * mb;
        float s = gamma[t] * rsqrtf(var + 1e-5f);
        stats[420 + t] = s;
        stats[548 + t] = beta[t] - s * mb;   // note: b_rl cancels inside BN
    }
    {
        int k = t >> 1, h = t & 1;
        float a1 = 0.f, a2 = 0.f;
        for (int c = 0; c < C; c++) {
            a1 += g1_wd[k * HC + h * C + c] * g1_ad[h * C + c];
            a2 += g2_wd[k * HC + h * C + c] * g2_ad[h * C + c];
        }
        stats[676 + k * 2 + h] = a1;
        stats[932 + k * 2 + h] = a2;
    }
}

// ---------------- K3: r0 = BN(x@W+b) (folded), + a_d1 reduction -------------------
__global__ __launch_bounds__(256) void k_r0(const float* __restrict__ x, const float* __restrict__ W,
    const float* __restrict__ stats, const float* __restrict__ vdsec, int NR,
    float* __restrict__ r0, float* __restrict__ a_d)
{
    __shared__ float Ws[DIN * C]; // row-major [k][c], 10 KB
    __shared__ float xr[2][DIN];
    __shared__ float red[8];
    int t = threadIdx.x;
    for (int i = t; i < DIN * C; i += 256) Ws[i] = W[i];
    int rowBase = blockIdx.x * 2;
    if (t < 2 * DIN) {
        int r = t / DIN, k = t % DIN;
        int row = rowBase + r;
        xr[r][k] = (row < NR) ? x[row * DIN + k] : 0.f;
    }
    __syncthreads();
    int r = t >> 7, c = t & 127;
    int row = rowBase + r;
    float dot = 0.f;
    #pragma unroll
    for (int k = 0; k < DIN; k++) dot += xr[r][k] * Ws[k * C + c];
    float val = stats[420 + c] * dot + stats[548 + c];
    if (row < NR) r0[(size_t)row * C + c] = val;
    float p0 = val * vdsec[c * 2 + 0], p1 = val * vdsec[c * 2 + 1];
    #pragma unroll
    for (int off = 32; off; off >>= 1) { p0 += __shfl_down(p0, off); p1 += __shfl_down(p1, off); }
    if ((t & 63) == 0) { red[(t >> 6) * 2] = p0; red[(t >> 6) * 2 + 1] = p1; }
    __syncthreads();
    if ((t & 127) == 0 && row < NR) {
        int w0 = t >> 6;
        a_d[row * 2 + 0] = red[w0 * 2 + 0] + red[(w0 + 1) * 2 + 0];
        a_d[row * 2 + 1] = red[w0 * 2 + 1] + red[(w0 + 1) * 2 + 1];
    }
}

// ---------------- K4/K5: hs = gather(table)[ids] @ ws, + a_s ----------------------
__global__ __launch_bounds__(256) void k_hs(const float* __restrict__ table,
    const int* __restrict__ ids, const float* __restrict__ ws, const float* __restrict__ att,
    int Ns, int renorm, float* __restrict__ hs, float* __restrict__ a_s)
{
    __shared__ float A[8][C];   // 4 KB
    __shared__ float attS[HC];
    __shared__ float red[17];
    int t = threadIdx.x;
    int rowBase = blockIdx.x * 8;
    attS[t] = att[t];
    #pragma unroll
    for (int j = 0; j < 4; j++) {
        int e = t + 256 * j;
        int r = e >> 7, cc = e & 127;
        int row = rowBase + r;
        float v = 0.f;
        if (row < Ns) { int g = ids[row]; v = table[(size_t)g * C + cc]; }
        A[r][cc] = v;
    }
    __syncthreads();
    if (renorm) {
        for (int r = 0; r < 8; r++) {
            float v = (t < 128) ? A[r][t] : 0.f;
            float ss = v * v;
            #pragma unroll
            for (int off = 32; off; off >>= 1) ss += __shfl_down(ss, off);
            if ((t & 63) == 0) red[t >> 6] = ss;
            __syncthreads();
            if (t == 0) {
                float nn = sqrtf(red[0] + red[1]);
                red[16] = (nn > 1.f) ? 1.f / (nn + 1e-7f) : 1.f;
            }
            __syncthreads();
            if (t < 128) A[r][t] *= red[16];
            __syncthreads();
        }
    }
    float acc[8];
    #pragma unroll
    for (int r = 0; r < 8; r++) acc[r] = 0.f;
    for (int k = 0; k < C; k++) {
        float b = ws[k * HC + t];
        #pragma unroll
        for (int r = 0; r < 8; r++) acc[r] += A[r][k] * b;
    }
    int h = t >> 7;
    float av = attS[t];
    for (int r = 0; r < 8; r++) {
        int row = rowBase + r;
        if (row < Ns) hs[(size_t)row * HC + t] = acc[r];
        float p = acc[r] * av;
        #pragma unroll
        for (int off = 32; off; off >>= 1) p += __shfl_down(p, off);
        if ((t & 63) == 0) red[t >> 6] = p;
        __syncthreads();
        if ((t & 127) == 0 && row < Ns) {
            int w0 = t >> 6;
            a_s[row * 2 + h] = red[w0] + red[w0 + 1];
        }
        __syncthreads();
    }
}

// ---------------- K6: per-edge exp + denominator atomics --------------------------
__global__ __launch_bounds__(256) void k_edgeA(const int* __restrict__ src, const int* __restrict__ dst,
    int E, int L, const float* __restrict__ a_s, const float* __restrict__ a_d,
    float* __restrict__ exb, float* __restrict__ den)
{
    int e = blockIdx.x * 256 + threadIdx.x;
    if (e >= E + L) return;
    int s, d;
    if (e < E) { s = src[e]; d = dst[e]; } else { s = d = e - E; }
    float e0 = a_s[s * 2 + 0] + a_d[d * 2 + 0];
    float e1 = a_s[s * 2 + 1] + a_d[d * 2 + 1];
    e0 = (e0 >= 0.f) ? e0 : 0.2f * e0;
    e1 = (e1 >= 0.f) ? e1 : 0.2f * e1;
    float x0 = __expf(e0), x1 = __expf(e1);
    exb[e * 2 + 0] = x0; exb[e * 2 + 1] = x1;
    atomicAdd(&den[d * 2 + 0], x0);
    atomicAdd(&den[d * 2 + 1], x1);
}

// ---------------- K7: weighted scatter of hs rows into acc ------------------------
__global__ __launch_bounds__(256) void k_scatter(const int* __restrict__ src, const int* __restrict__ dst,
    int E, int L, const float* __restrict__ exb, const float* __restrict__ den,
    const float* __restrict__ hs, float* __restrict__ acc)
{
    int t = threadIdx.x;
    int e = blockIdx.x * 2 + (t >> 7);
    if (e >= E + L) return;
    int c = t & 127;
    int s, d;
    if (e < E) { s = src[e]; d = dst[e]; } else { s = d = e - E; }
    float a0 = exb[e * 2 + 0] / (den[d * 2 + 0] + 1e-16f);
    float a1 = exb[e * 2 + 1] / (den[d * 2 + 1] + 1e-16f);
    float val = 0.5f * (hs[(size_t)s * HC + c] * a0 + hs[(size_t)s * HC + C + c] * a1);
    atomicAdd(&acc[(size_t)d * C + c], val);
}

// ---------------- K8: r1 = r0 + acc + b1 (in place), + a_d2 -----------------------
__global__ __launch_bounds__(256) void k_fin1(float* __restrict__ r0, const float* __restrict__ acc,
    const float* __restrict__ bias, const float* __restrict__ vdsec, int NR, float* __restrict__ a_d)
{
    __shared__ float red[8];
    int t = threadIdx.x;
    int r = t >> 7, c = t & 127;
    int row = blockIdx.x * 2 + r;
    float val = 0.f;
    if (row < NR) {
        val = r0[(size_t)row * C + c] + acc[(size_t)row * C + c] + bias[c];
        r0[(size_t)row * C + c] = val;
    }
    float p0 = val * vdsec[c * 2 + 0], p1 = val * vdsec[c * 2 + 1];
    #pragma unroll
    for (int off = 32; off; off >>= 1) { p0 += __shfl_down(p0, off); p1 += __shfl_down(p1, off); }
    if ((t & 63) == 0) { red[(t >> 6) * 2] = p0; red[(t >> 6) * 2 + 1] = p1; }
    __syncthreads();
    if ((t & 127) == 0 && row < NR) {
        int w0 = t >> 6;
        a_d[row * 2 + 0] = red[w0 * 2 + 0] + red[(w0 + 1) * 2 + 0];
        a_d[row * 2 + 1] = red[w0 * 2 + 1] + red[(w0 + 1) * 2 + 1];
    }
}

// ---------------- K9: out = acc + b2 ----------------------------------------------
__global__ __launch_bounds__(256) void k_out(const float* __restrict__ acc,
    const float* __restrict__ bias, long long n, float* __restrict__ out)
{
    long long i = (long long)blockIdx.x * 256 + threadIdx.x;
    if (i >= n) return;
    int c = (int)(i & 127);
    out[i] = acc[i] + bias[c];
}

extern "C" void kernel_launch(void* const* d_in, const int* in_sizes, int n_in,
                              void* d_out, int out_size, void* d_ws, size_t ws_size,
                              hipStream_t stream) {
    const int*   user_ids       = (const int*)d_in[0];
    const int*   ingredient_ids = (const int*)d_in[1];
    const float* recipe_x       = (const float*)d_in[2];
    const int*   ing_src        = (const int*)d_in[3];
    const int*   ing_dst        = (const int*)d_in[4];
    const int*   ub_src         = (const int*)d_in[5];
    const int*   ub_dst         = (const int*)d_in[6];
    const float* user_table     = (const float*)d_in[7];
    const float* ing_table      = (const float*)d_in[8];
    const float* W_rl           = (const float*)d_in[9];
    const float* b_rl           = (const float*)d_in[10];
    const float* bn_gamma       = (const float*)d_in[11];
    const float* bn_beta        = (const float*)d_in[12];
    const float* g1_ws          = (const float*)d_in[13];
    const float* g1_wd          = (const float*)d_in[14];
    const float* g1_as          = (const float*)d_in[15];
    const float* g1_ad          = (const float*)d_in[16];
    const float* g1_b           = (const float*)d_in[17];
    const float* g2_ws          = (const float*)d_in[18];
    const float* g2_wd          = (const float*)d_in[19];
    const float* g2_as          = (const float*)d_in[20];
    const float* g2_ad          = (const float*)d_in[21];
    const float* g2_b           = (const float*)d_in[22];

    int NU = in_sizes[0];
    int NI = in_sizes[1];
    int NR = in_sizes[2] / DIN;
    int E1 = in_sizes[3];
    int E2 = in_sizes[5];
    int Nmax = (NI > NU) ? NI : NU;
    int L1 = (NI < NR) ? NI : NR;
    int L2n = (NU < NR) ? NU : NR;
    int Emax = ((E1 + L1) > (E2 + L2n)) ? (E1 + L1) : (E2 + L2n);

    char* w = (char*)d_ws;
    float* r0   = (float*)w;                w += (size_t)NR * C * 4;
    float* acc  = (float*)w;                w += (size_t)NR * C * 4;
    float* hs   = (float*)w;                w += (size_t)Nmax * HC * 4;
    float* a_s  = (float*)w;                w += (size_t)Nmax * 2 * 4;
    float* a_d  = (float*)w;                w += (size_t)NR * 2 * 4;
    float* den  = (float*)w;                w += (size_t)NR * 2 * 4;
    float* exb  = (float*)w;                w += (size_t)Emax * 2 * 4;
    float* stats= (float*)w;                w += 1280 * 4;

    // ---- GAT1 phase ----
    hipMemsetAsync(stats, 0, 420 * 4, stream);
    hipMemsetAsync(den, 0, (size_t)NR * 2 * 4, stream);
    hipMemsetAsync(acc, 0, (size_t)NR * C * 4, stream);

    k_stats<<<(NR + 255) / 256, 256, 0, stream>>>(recipe_x, NR, stats);
    k_precomp<<<1, 256, 0, stream>>>(stats, W_rl, b_rl, bn_gamma, bn_beta,
                                     g1_wd, g1_ad, g2_wd, g2_ad, 1.0f / NR);
    k_hs<<<(NI + 7) / 8, 256, 0, stream>>>(ing_table, ingredient_ids, g1_ws, g1_as, NI, 0, hs, a_s);
    k_r0<<<(NR + 1) / 2, 256, 0, stream>>>(recipe_x, W_rl, stats, stats + 676, NR, r0, a_d);
    k_edgeA<<<(E1 + L1 + 255) / 256, 256, 0, stream>>>(ing_src, ing_dst, E1, L1, a_s, a_d, exb, den);
    k_scatter<<<(E1 + L1 + 1) / 2, 256, 0, stream>>>(ing_src, ing_dst, E1, L1, exb, den, hs, acc);
    k_fin1<<<(NR + 1) / 2, 256, 0, stream>>>(r0, acc, g1_b, stats + 932, NR, a_d);

    // ---- GAT2 phase ----
    hipMemsetAsync(den, 0, (size_t)NR * 2 * 4, stream);
    hipMemsetAsync(acc, 0, (size_t)NR * C * 4, stream);
    k_hs<<<(NU + 7) / 8, 256, 0, stream>>>(user_table, user_ids, g2_ws, g2_as, NU, 1, hs, a_s);
    k_edgeA<<<(E2 + L2n + 255) / 256, 256, 0, stream>>>(ub_src, ub_dst, E2, L2n, a_s, a_d, exb, den);
    k_scatter<<<(E2 + L2n + 1) / 2, 256, 0, stream>>>(ub_src, ub_dst, E2, L2n, exb, den, hs, acc);
    k_out<<<(int)(((long long)NR * C + 255) / 256), 256, 0, stream>>>(acc, g2_b, (long long)NR * C, (float*)d_out);
}

// Round 3
// 785.895 us; speedup vs baseline: 1.5097x; 1.5097x over previous
//
#include <hip/hip_runtime.h>
#include <hip/hip_bf16.h>
#include <math.h>

#define DIN 20
#define C 128
#define HC 256

// ---------------- K1: BN stats (second moment 20x20 + column sums) ----------------
__global__ __launch_bounds__(256) void k_stats(const float* __restrict__ x, int NR,
                                               float* __restrict__ stats)
// stats[0..399] = M (full 20x20), stats[400..419] = colsum
{
    __shared__ float L[256][DIN]; // 20 KB
    int t = threadIdx.x;
    int r = blockIdx.x * 256 + t;
    if (r < NR) {
        #pragma unroll
        for (int k = 0; k < DIN; k++) L[t][k] = x[r * DIN + k];
    } else {
        #pragma unroll
        for (int k = 0; k < DIN; k++) L[t][k] = 0.f;
    }
    __syncthreads();
    if (t < 210) {
        int p = 0, q = t;
        while (q >= DIN - p) { q -= (DIN - p); p++; }
        q += p;
        float acc = 0.f;
        for (int rr = 0; rr < 256; rr++) acc += L[rr][p] * L[rr][q];
        atomicAdd(&stats[p * DIN + q], acc);
        if (p != q) atomicAdd(&stats[q * DIN + p], acc);
    } else if (t < 230) {
        int k = t - 210;
        float acc = 0.f;
        for (int rr = 0; rr < 256; rr++) acc += L[rr][k];
        atomicAdd(&stats[400 + k], acc);
    }
}

// ---------------- K2: fold BN into scale/shift; precompute v_d = w_d @ att_d ------
__global__ __launch_bounds__(256) void k_precomp(float* __restrict__ stats,
    const float* __restrict__ W, const float* __restrict__ b,
    const float* __restrict__ gamma, const float* __restrict__ beta,
    const float* __restrict__ g1_wd, const float* __restrict__ g1_ad,
    const float* __restrict__ g2_wd, const float* __restrict__ g2_ad, float invN)
// writes stats[420..547]=s, [548..675]=tsh, [676..931]=vd1[k*2+h], [932..1187]=vd2
{
    int t = threadIdx.x;
    if (t < C) {
        float w[DIN];
        #pragma unroll
        for (int k = 0; k < DIN; k++) w[k] = W[k * C + t];
        float mb = 0.f;
        #pragma unroll
        for (int k = 0; k < DIN; k++) mb += stats[400 + k] * invN * w[k];
        float e2 = 0.f;
        for (int p = 0; p < DIN; p++) {
            float acc2 = 0.f;
            for (int q = 0; q < DIN; q++) acc2 += stats[p * DIN + q] * w[q];
            e2 += w[p] * acc2;
        }
        e2 *= invN;
        float var = e2 - mb * mb;
        float s = gamma[t] * rsqrtf(var + 1e-5f);
        stats[420 + t] = s;
        stats[548 + t] = beta[t] - s * mb;   // b_rl cancels inside BN
    }
    {
        int k = t >> 1, h = t & 1;
        float a1 = 0.f, a2 = 0.f;
        for (int c = 0; c < C; c++) {
            a1 += g1_wd[k * HC + h * C + c] * g1_ad[h * C + c];
            a2 += g2_wd[k * HC + h * C + c] * g2_ad[h * C + c];
        }
        stats[676 + k * 2 + h] = a1;
        stats[932 + k * 2 + h] = a2;
    }
}

// ---------------- K3: r0 = BN(x@W+b) (folded), + a_d1 reduction -------------------
__global__ __launch_bounds__(256) void k_r0(const float* __restrict__ x, const float* __restrict__ W,
    const float* __restrict__ stats, const float* __restrict__ vdsec, int NR,
    float* __restrict__ r0, float* __restrict__ a_d)
{
    __shared__ float Ws[DIN * C]; // row-major [k][c], 10 KB
    __shared__ float xr[2][DIN];
    __shared__ float red[8];
    int t = threadIdx.x;
    for (int i = t; i < DIN * C; i += 256) Ws[i] = W[i];
    int rowBase = blockIdx.x * 2;
    if (t < 2 * DIN) {
        int r = t / DIN, k = t % DIN;
        int row = rowBase + r;
        xr[r][k] = (row < NR) ? x[row * DIN + k] : 0.f;
    }
    __syncthreads();
    int r = t >> 7, c = t & 127;
    int row = rowBase + r;
    float dot = 0.f;
    #pragma unroll
    for (int k = 0; k < DIN; k++) dot += xr[r][k] * Ws[k * C + c];
    float val = stats[420 + c] * dot + stats[548 + c];
    if (row < NR) r0[(size_t)row * C + c] = val;
    float p0 = val * vdsec[c * 2 + 0], p1 = val * vdsec[c * 2 + 1];
    #pragma unroll
    for (int off = 32; off; off >>= 1) { p0 += __shfl_down(p0, off); p1 += __shfl_down(p1, off); }
    if ((t & 63) == 0) { red[(t >> 6) * 2] = p0; red[(t >> 6) * 2 + 1] = p1; }
    __syncthreads();
    if ((t & 127) == 0 && row < NR) {
        int w0 = t >> 6;
        a_d[row * 2 + 0] = red[w0 * 2 + 0] + red[(w0 + 1) * 2 + 0];
        a_d[row * 2 + 1] = red[w0 * 2 + 1] + red[(w0 + 1) * 2 + 1];
    }
}

// ---------------- K4: hs = gather(table)[ids] @ ws, + a_s -------------------------
__global__ __launch_bounds__(256) void k_hs(const float* __restrict__ table,
    const int* __restrict__ ids, const float* __restrict__ ws, const float* __restrict__ att,
    int Ns, int renorm, float* __restrict__ hs, float* __restrict__ a_s)
{
    __shared__ float A[8][C];   // 4 KB
    __shared__ float attS[HC];
    __shared__ float red[17];
    int t = threadIdx.x;
    int rowBase = blockIdx.x * 8;
    attS[t] = att[t];
    #pragma unroll
    for (int j = 0; j < 4; j++) {
        int e = t + 256 * j;
        int r = e >> 7, cc = e & 127;
        int row = rowBase + r;
        float v = 0.f;
        if (row < Ns) { int g = ids[row]; v = table[(size_t)g * C + cc]; }
        A[r][cc] = v;
    }
    __syncthreads();
    if (renorm) {
        for (int r = 0; r < 8; r++) {
            float v = (t < 128) ? A[r][t] : 0.f;
            float ss = v * v;
            #pragma unroll
            for (int off = 32; off; off >>= 1) ss += __shfl_down(ss, off);
            if ((t & 63) == 0) red[t >> 6] = ss;
            __syncthreads();
            if (t == 0) {
                float nn = sqrtf(red[0] + red[1]);
                red[16] = (nn > 1.f) ? 1.f / (nn + 1e-7f) : 1.f;
            }
            __syncthreads();
            if (t < 128) A[r][t] *= red[16];
            __syncthreads();
        }
    }
    float acc[8];
    #pragma unroll
    for (int r = 0; r < 8; r++) acc[r] = 0.f;
    for (int k = 0; k < C; k++) {
        float b = ws[k * HC + t];
        #pragma unroll
        for (int r = 0; r < 8; r++) acc[r] += A[r][k] * b;
    }
    int h = t >> 7;
    float av = attS[t];
    for (int r = 0; r < 8; r++) {
        int row = rowBase + r;
        if (row < Ns) hs[(size_t)row * HC + t] = acc[r];
        float p = acc[r] * av;
        #pragma unroll
        for (int off = 32; off; off >>= 1) p += __shfl_down(p, off);
        if ((t & 63) == 0) red[t >> 6] = p;
        __syncthreads();
        if ((t & 127) == 0 && row < Ns) {
            int w0 = t >> 6;
            a_s[row * 2 + h] = red[w0] + red[w0 + 1];
        }
        __syncthreads();
    }
}

// ---------------- CSR build: histogram, 2-level exclusive scan, fill --------------
__global__ __launch_bounds__(256) void k_hist(const int* __restrict__ dst, int E, int L,
                                              int* __restrict__ cnt)
{
    int e = blockIdx.x * 256 + threadIdx.x;
    if (e >= E + L) return;
    int d = (e < E) ? dst[e] : (e - E);
    atomicAdd(&cnt[d], 1);
}

__global__ __launch_bounds__(256) void k_scan_bsum(const int* __restrict__ cnt, int n,
                                                   int* __restrict__ bsum)
{
    __shared__ int s[256];
    int t = threadIdx.x;
    int base = blockIdx.x * 1024;
    int a = 0;
    #pragma unroll
    for (int j = 0; j < 4; j++) { int i = base + t * 4 + j; a += (i < n) ? cnt[i] : 0; }
    s[t] = a; __syncthreads();
    for (int off = 128; off; off >>= 1) { if (t < off) s[t] += s[t + off]; __syncthreads(); }
    if (t == 0) bsum[blockIdx.x] = s[0];
}

__global__ void k_scan_top(int* __restrict__ bsum, int nb, int* __restrict__ total)
{
    if (threadIdx.x == 0) {
        int acc = 0;
        for (int i = 0; i < nb; i++) { int v = bsum[i]; bsum[i] = acc; acc += v; }
        *total = acc;
    }
}

__global__ __launch_bounds__(256) void k_scan_out(const int* __restrict__ cnt, int n,
    const int* __restrict__ bsum, int* __restrict__ off, int* __restrict__ cursor)
{
    __shared__ int s[256];
    int t = threadIdx.x;
    int base = blockIdx.x * 1024;
    int v[4]; int a = 0;
    #pragma unroll
    for (int j = 0; j < 4; j++) { int i = base + t * 4 + j; v[j] = (i < n) ? cnt[i] : 0; a += v[j]; }
    s[t] = a; __syncthreads();
    for (int o = 1; o < 256; o <<= 1) {
        int x = (t >= o) ? s[t - o] : 0;
        __syncthreads();
        s[t] += x;
        __syncthreads();
    }
    int excl = (t == 0) ? 0 : s[t - 1];
    int b = bsum[blockIdx.x] + excl;
    #pragma unroll
    for (int j = 0; j < 4; j++) {
        int i = base + t * 4 + j;
        if (i < n) { off[i] = b; cursor[i] = b; }
        b += v[j];
    }
}

__global__ __launch_bounds__(256) void k_fill(const int* __restrict__ src, const int* __restrict__ dst,
    int E, int L, int* __restrict__ cursor, int* __restrict__ sorted)
{
    int e = blockIdx.x * 256 + threadIdx.x;
    if (e >= E + L) return;
    int s, d;
    if (e < E) { s = src[e]; d = dst[e]; } else { s = d = e - E; }
    int p = atomicAdd(&cursor[d], 1);
    sorted[p] = s;
}

// ---------------- K_agg: per-dst softmax + gather-aggregate (wave per dst) --------
// mode 0 (GAT1): out = a_d2[d][2] from (r0 + agg + bias) . vd
// mode 1 (GAT2): out_final[d*C..] = agg + bias
__global__ __launch_bounds__(256) void k_agg(const int* __restrict__ off, const int* __restrict__ sorted,
    const float* __restrict__ a_s, const float* __restrict__ a_d,
    const float* __restrict__ hs, int NR, int mode,
    const float* __restrict__ r0, const float* __restrict__ bias, const float* __restrict__ vd,
    float* __restrict__ out_ad, float* __restrict__ out_final)
{
    int wave = threadIdx.x >> 6, lane = threadIdx.x & 63;
    int d = blockIdx.x * 4 + wave;
    if (d >= NR) return;
    int beg = off[d], end = off[d + 1];
    float ad0 = a_d[d * 2 + 0], ad1 = a_d[d * 2 + 1];
    // denominator (strided over lanes, wave reduce)
    float den0 = 0.f, den1 = 0.f;
    for (int j = beg + lane; j < end; j += 64) {
        int s = sorted[j];
        float e0 = a_s[s * 2 + 0] + ad0;
        float e1 = a_s[s * 2 + 1] + ad1;
        e0 = (e0 >= 0.f) ? e0 : 0.2f * e0;
        e1 = (e1 >= 0.f) ? e1 : 0.2f * e1;
        den0 += __expf(e0); den1 += __expf(e1);
    }
    #pragma unroll
    for (int o = 32; o; o >>= 1) { den0 += __shfl_down(den0, o); den1 += __shfl_down(den1, o); }
    den0 = __shfl(den0, 0); den1 = __shfl(den1, 0);
    float inv0 = 1.f / (den0 + 1e-16f), inv1 = 1.f / (den1 + 1e-16f);
    // weighted gather: lane holds channels {lane, lane+64} per head
    float acc0 = 0.f, acc1 = 0.f, acc2 = 0.f, acc3 = 0.f;
    for (int j = beg; j < end; j++) {
        int s = sorted[j];
        float e0 = a_s[s * 2 + 0] + ad0;
        float e1 = a_s[s * 2 + 1] + ad1;
        e0 = (e0 >= 0.f) ? e0 : 0.2f * e0;
        e1 = (e1 >= 0.f) ? e1 : 0.2f * e1;
        float w0 = __expf(e0) * inv0, w1 = __expf(e1) * inv1;
        const float* hrow = hs + (size_t)s * HC;
        acc0 += hrow[lane]       * w0;
        acc1 += hrow[64 + lane]  * w0;
        acc2 += hrow[128 + lane] * w1;
        acc3 += hrow[192 + lane] * w1;
    }
    float c0 = 0.5f * (acc0 + acc2);   // channel lane
    float c1 = 0.5f * (acc1 + acc3);   // channel lane+64
    if (mode == 1) {
        out_final[(size_t)d * C + lane]      = c0 + bias[lane];
        out_final[(size_t)d * C + 64 + lane] = c1 + bias[64 + lane];
    } else {
        float v0 = c0 + r0[(size_t)d * C + lane]      + bias[lane];
        float v1 = c1 + r0[(size_t)d * C + 64 + lane] + bias[64 + lane];
        float p0 = v0 * vd[lane * 2 + 0] + v1 * vd[(64 + lane) * 2 + 0];
        float p1 = v0 * vd[lane * 2 + 1] + v1 * vd[(64 + lane) * 2 + 1];
        #pragma unroll
        for (int o = 32; o; o >>= 1) { p0 += __shfl_down(p0, o); p1 += __shfl_down(p1, o); }
        if (lane == 0) { out_ad[d * 2 + 0] = p0; out_ad[d * 2 + 1] = p1; }
    }
}

extern "C" void kernel_launch(void* const* d_in, const int* in_sizes, int n_in,
                              void* d_out, int out_size, void* d_ws, size_t ws_size,
                              hipStream_t stream) {
    const int*   user_ids       = (const int*)d_in[0];
    const int*   ingredient_ids = (const int*)d_in[1];
    const float* recipe_x       = (const float*)d_in[2];
    const int*   ing_src        = (const int*)d_in[3];
    const int*   ing_dst        = (const int*)d_in[4];
    const int*   ub_src         = (const int*)d_in[5];
    const int*   ub_dst         = (const int*)d_in[6];
    const float* user_table     = (const float*)d_in[7];
    const float* ing_table      = (const float*)d_in[8];
    const float* W_rl           = (const float*)d_in[9];
    const float* b_rl           = (const float*)d_in[10];
    const float* bn_gamma       = (const float*)d_in[11];
    const float* bn_beta        = (const float*)d_in[12];
    const float* g1_ws          = (const float*)d_in[13];
    const float* g1_wd          = (const float*)d_in[14];
    const float* g1_as          = (const float*)d_in[15];
    const float* g1_ad          = (const float*)d_in[16];
    const float* g1_b           = (const float*)d_in[17];
    const float* g2_ws          = (const float*)d_in[18];
    const float* g2_wd          = (const float*)d_in[19];
    const float* g2_as          = (const float*)d_in[20];
    const float* g2_ad          = (const float*)d_in[21];
    const float* g2_b           = (const float*)d_in[22];

    int NU = in_sizes[0];
    int NI = in_sizes[1];
    int NR = in_sizes[2] / DIN;
    int E1 = in_sizes[3];
    int E2 = in_sizes[5];
    int Nmax = (NI > NU) ? NI : NU;
    int L1 = (NI < NR) ? NI : NR;
    int L2 = (NU < NR) ? NU : NR;
    int Emax = ((E1 + L1) > (E2 + L2)) ? (E1 + L1) : (E2 + L2);
    int nb = (NR + 1023) / 1024;

    char* w = (char*)d_ws;
    float* r0    = (float*)w;  w += (size_t)NR * C * 4;
    float* hs    = (float*)w;  w += (size_t)Nmax * HC * 4;
    float* a_s   = (float*)w;  w += (size_t)Nmax * 2 * 4;
    float* a_d   = (float*)w;  w += (size_t)NR * 2 * 4;
    float* stats = (float*)w;  w += 1280 * 4;
    int*   cnt   = (int*)w;    w += (size_t)NR * 4;
    int*   off   = (int*)w;    w += (size_t)(NR + 1) * 4;
    int*   cursor= (int*)w;    w += (size_t)NR * 4;
    int*   bsum  = (int*)w;    w += (size_t)(nb + 1) * 4;
    int*   sorted= (int*)w;    w += (size_t)Emax * 4;

    // ================= GAT1 (ingredient -> recipe) =================
    hipMemsetAsync(stats, 0, 420 * 4, stream);
    hipMemsetAsync(cnt, 0, (size_t)NR * 4, stream);

    k_stats<<<(NR + 255) / 256, 256, 0, stream>>>(recipe_x, NR, stats);
    k_precomp<<<1, 256, 0, stream>>>(stats, W_rl, b_rl, bn_gamma, bn_beta,
                                     g1_wd, g1_ad, g2_wd, g2_ad, 1.0f / NR);
    k_hs<<<(NI + 7) / 8, 256, 0, stream>>>(ing_table, ingredient_ids, g1_ws, g1_as, NI, 0, hs, a_s);
    k_r0<<<(NR + 1) / 2, 256, 0, stream>>>(recipe_x, W_rl, stats, stats + 676, NR, r0, a_d);
    k_hist<<<(E1 + L1 + 255) / 256, 256, 0, stream>>>(ing_dst, E1, L1, cnt);
    k_scan_bsum<<<nb, 256, 0, stream>>>(cnt, NR, bsum);
    k_scan_top<<<1, 64, 0, stream>>>(bsum, nb, off + NR);
    k_scan_out<<<nb, 256, 0, stream>>>(cnt, NR, bsum, off, cursor);
    k_fill<<<(E1 + L1 + 255) / 256, 256, 0, stream>>>(ing_src, ing_dst, E1, L1, cursor, sorted);
    // a_d is rewritten in place with a_d2 (per-dst read-then-write, safe)
    k_agg<<<(NR + 3) / 4, 256, 0, stream>>>(off, sorted, a_s, a_d, hs, NR, 0,
                                            r0, g1_b, stats + 932, a_d, (float*)nullptr);

    // ================= GAT2 (user -> recipe) =================
    hipMemsetAsync(cnt, 0, (size_t)NR * 4, stream);
    k_hs<<<(NU + 7) / 8, 256, 0, stream>>>(user_table, user_ids, g2_ws, g2_as, NU, 1, hs, a_s);
    k_hist<<<(E2 + L2 + 255) / 256, 256, 0, stream>>>(ub_dst, E2, L2, cnt);
    k_scan_bsum<<<nb, 256, 0, stream>>>(cnt, NR, bsum);
    k_scan_top<<<1, 64, 0, stream>>>(bsum, nb, off + NR);
    k_scan_out<<<nb, 256, 0, stream>>>(cnt, NR, bsum, off, cursor);
    k_fill<<<(E2 + L2 + 255) / 256, 256, 0, stream>>>(ub_src, ub_dst, E2, L2, cursor, sorted);
    k_agg<<<(NR + 3) / 4, 256, 0, stream>>>(off, sorted, a_s, a_d, hs, NR, 1,
                                            (const float*)nullptr, g2_b, (const float*)nullptr,
                                            (float*)nullptr, (float*)d_out);
}

// Round 4
// 745.007 us; speedup vs baseline: 1.5925x; 1.0549x over previous
//
#include <hip/hip_runtime.h>
#include <hip/hip_bf16.h>
#include <math.h>

#define DIN 20
#define C 128
#define HC 256

typedef unsigned short u16;

__device__ __forceinline__ float bfbits2f(unsigned int lo16) {
    return __uint_as_float(lo16 << 16);
}
__device__ __forceinline__ u16 f2bf_rne(float f) {
    unsigned int b = __float_as_uint(f);
    return (u16)((b + 0x7FFFu + ((b >> 16) & 1u)) >> 16);
}

// ---------------- K1: BN stats (second moment 20x20 + column sums) ----------------
__global__ __launch_bounds__(256) void k_stats(const float* __restrict__ x, int NR,
                                               float* __restrict__ stats)
// stats[0..399] = M (full 20x20), stats[400..419] = colsum
{
    __shared__ float L[256][DIN];
    int t = threadIdx.x;
    int r = blockIdx.x * 256 + t;
    if (r < NR) {
        #pragma unroll
        for (int k = 0; k < DIN; k++) L[t][k] = x[r * DIN + k];
    } else {
        #pragma unroll
        for (int k = 0; k < DIN; k++) L[t][k] = 0.f;
    }
    __syncthreads();
    if (t < 210) {
        int p = 0, q = t;
        while (q >= DIN - p) { q -= (DIN - p); p++; }
        q += p;
        float acc = 0.f;
        for (int rr = 0; rr < 256; rr++) acc += L[rr][p] * L[rr][q];
        atomicAdd(&stats[p * DIN + q], acc);
        if (p != q) atomicAdd(&stats[q * DIN + p], acc);
    } else if (t < 230) {
        int k = t - 210;
        float acc = 0.f;
        for (int rr = 0; rr < 256; rr++) acc += L[rr][k];
        atomicAdd(&stats[400 + k], acc);
    }
}

// ---------------- K2: fold BN; vd1/vd2 = w_d @ att_d; cb = b1 . vd2 ---------------
// stats layout: [420..547]=BN scale, [548..675]=BN shift,
//               [676..931]=vd1[k*2+h], [932..1187]=vd2[k*2+h], [1188..1189]=cb[h]
__global__ __launch_bounds__(256) void k_precomp(float* __restrict__ stats,
    const float* __restrict__ W,
    const float* __restrict__ gamma, const float* __restrict__ beta,
    const float* __restrict__ g1_wd, const float* __restrict__ g1_ad,
    const float* __restrict__ g2_wd, const float* __restrict__ g2_ad,
    const float* __restrict__ g1b, float invN)
{
    int t = threadIdx.x;
    if (t < C) {
        float w[DIN];
        #pragma unroll
        for (int k = 0; k < DIN; k++) w[k] = W[k * C + t];
        float mb = 0.f;
        #pragma unroll
        for (int k = 0; k < DIN; k++) mb += stats[400 + k] * invN * w[k];
        float e2 = 0.f;
        for (int p = 0; p < DIN; p++) {
            float acc2 = 0.f;
            for (int q = 0; q < DIN; q++) acc2 += stats[p * DIN + q] * w[q];
            e2 += w[p] * acc2;
        }
        e2 *= invN;
        float var = e2 - mb * mb;
        float s = gamma[t] * rsqrtf(var + 1e-5f);
        stats[420 + t] = s;
        stats[548 + t] = beta[t] - s * mb;   // b_rl cancels inside BN
    }
    {
        int k = t >> 1, h = t & 1;
        float a1 = 0.f, a2 = 0.f;
        for (int c = 0; c < C; c++) {
            a1 += g1_wd[k * HC + h * C + c] * g1_ad[h * C + c];
            a2 += g2_wd[k * HC + h * C + c] * g2_ad[h * C + c];
        }
        stats[676 + k * 2 + h] = a1;
        stats[932 + k * 2 + h] = a2;
    }
    __syncthreads();
    if (t < 2) {
        float cb = 0.f;
        for (int k = 0; k < C; k++) cb += g1b[k] * stats[932 + k * 2 + t];
        stats[1188 + t] = cb;
    }
}

// ---------------- K3: BN(x@W) folded -> only a_d1 = r0.vd1 and advd = r0.vd2 ------
__global__ __launch_bounds__(256) void k_r0(const float* __restrict__ x, const float* __restrict__ W,
    const float* __restrict__ stats, int NR,
    float* __restrict__ a_d, float* __restrict__ advd)
{
    __shared__ float xr[16 * DIN];
    __shared__ float red[16];
    int t = threadIdx.x;
    int rowBase = blockIdx.x * 16;
    for (int i = t; i < 16 * DIN; i += 256) {
        int gi = rowBase * DIN + i;
        xr[i] = (gi < NR * DIN) ? x[gi] : 0.f;
    }
    int c = t & 127;
    int half = t >> 7;       // 0 or 1
    int wv = t >> 6;         // wave 0..3
    float w[DIN];
    #pragma unroll
    for (int k = 0; k < DIN; k++) w[k] = W[k * C + c];
    float s  = stats[420 + c], sh = stats[548 + c];
    float v10 = stats[676 + c * 2 + 0], v11 = stats[676 + c * 2 + 1];
    float v20 = stats[932 + c * 2 + 0], v21 = stats[932 + c * 2 + 1];
    __syncthreads();
    for (int p = 0; p < 8; p++) {
        int lr = 2 * p + half;
        float dot = 0.f;
        #pragma unroll
        for (int k = 0; k < DIN; k++) dot += w[k] * xr[lr * DIN + k];
        float val = s * dot + sh;
        float p0 = val * v10, p1 = val * v11, q0 = val * v20, q1 = val * v21;
        #pragma unroll
        for (int o = 32; o; o >>= 1) {
            p0 += __shfl_down(p0, o); p1 += __shfl_down(p1, o);
            q0 += __shfl_down(q0, o); q1 += __shfl_down(q1, o);
        }
        if ((t & 63) == 0) {
            red[wv * 4 + 0] = p0; red[wv * 4 + 1] = p1;
            red[wv * 4 + 2] = q0; red[wv * 4 + 3] = q1;
        }
        __syncthreads();
        int rowA = rowBase + 2 * p, rowB = rowA + 1;
        if (t == 0 && rowA < NR) {
            a_d[rowA * 2 + 0]  = red[0] + red[4];
            a_d[rowA * 2 + 1]  = red[1] + red[5];
            advd[rowA * 2 + 0] = red[2] + red[6];
            advd[rowA * 2 + 1] = red[3] + red[7];
        }
        if (t == 128 && rowB < NR) {
            a_d[rowB * 2 + 0]  = red[8]  + red[12];
            a_d[rowB * 2 + 1]  = red[9]  + red[13];
            advd[rowB * 2 + 0] = red[10] + red[14];
            advd[rowB * 2 + 1] = red[11] + red[15];
        }
        __syncthreads();
    }
}

// ---------------- K4: hs16 = bf16(gather(table)[ids] @ ws), + a_s -----------------
__global__ __launch_bounds__(256) void k_hs(const float* __restrict__ table,
    const int* __restrict__ ids, const float* __restrict__ ws, const float* __restrict__ att,
    int Ns, int renorm, u16* __restrict__ hs16, float* __restrict__ a_s)
{
    __shared__ float A[16][C];   // 8 KB
    __shared__ float attS[HC];
    __shared__ float red[64];
    int t = threadIdx.x;
    int rowBase = blockIdx.x * 16;
    attS[t] = att[t];
    #pragma unroll
    for (int j = 0; j < 8; j++) {
        int idx = t + 256 * j;
        int r = idx >> 7, cc = idx & 127;
        int row = rowBase + r;
        float v = 0.f;
        if (row < Ns) v = table[(size_t)ids[row] * C + cc];
        A[r][cc] = v;
    }
    __syncthreads();
    if (renorm) {
        int wv = t >> 6, l = t & 63;
        #pragma unroll
        for (int rr = 0; rr < 4; rr++) {
            int r = wv * 4 + rr;
            float v1 = A[r][l], v2 = A[r][l + 64];
            float ss = v1 * v1 + v2 * v2;
            #pragma unroll
            for (int o = 32; o; o >>= 1) ss += __shfl_down(ss, o);
            ss = __shfl(ss, 0);
            float nn = sqrtf(ss);
            float f = (nn > 1.f) ? 1.f / (nn + 1e-7f) : 1.f;
            A[r][l] = v1 * f; A[r][l + 64] = v2 * f;
        }
        __syncthreads();
    }
    float acc[16];
    #pragma unroll
    for (int r = 0; r < 16; r++) acc[r] = 0.f;
    #pragma unroll 4
    for (int k = 0; k < C; k++) {
        float b = ws[k * HC + t];
        #pragma unroll
        for (int r = 0; r < 16; r++) acc[r] += A[r][k] * b;
    }
    int wv = t >> 6;
    #pragma unroll
    for (int r = 0; r < 16; r++) {
        float p = acc[r] * attS[t];
        #pragma unroll
        for (int o = 32; o; o >>= 1) p += __shfl_down(p, o);
        if ((t & 63) == 0) red[wv * 16 + r] = p;
    }
    __syncthreads();
    if (t < 32) {
        int h = t >> 4, r = t & 15;
        int row = rowBase + r;
        if (row < Ns) a_s[row * 2 + h] = red[(2 * h) * 16 + r] + red[(2 * h + 1) * 16 + r];
    }
    #pragma unroll
    for (int r = 0; r < 16; r++) {
        int row = rowBase + r;
        if (row < Ns) hs16[(size_t)row * HC + t] = f2bf_rne(acc[r]);
    }
}

// ---------------- Combined CSR build for both graphs ------------------------------
__global__ __launch_bounds__(256) void k_hist2(const int* __restrict__ dst1, const int* __restrict__ dst2,
    int E1, int L1, int E2, int L2, int NR, int* __restrict__ cnt)
{
    int i = blockIdx.x * 256 + threadIdx.x;
    int T1 = E1 + L1, T = T1 + E2 + L2;
    if (i >= T) return;
    int d;
    if (i < T1) d = (i < E1) ? dst1[i] : (i - E1);
    else { int k = i - T1; d = NR + ((k < E2) ? dst2[k] : (k - E2)); }
    atomicAdd(&cnt[d], 1);
}

__global__ __launch_bounds__(256) void k_scan_bsum(const int* __restrict__ cnt, int n,
                                                   int* __restrict__ bsum)
{
    __shared__ int s[256];
    int t = threadIdx.x;
    int base = blockIdx.x * 1024;
    int a = 0;
    #pragma unroll
    for (int j = 0; j < 4; j++) { int i = base + t * 4 + j; a += (i < n) ? cnt[i] : 0; }
    s[t] = a; __syncthreads();
    for (int off = 128; off; off >>= 1) { if (t < off) s[t] += s[t + off]; __syncthreads(); }
    if (t == 0) bsum[blockIdx.x] = s[0];
}

__global__ void k_scan_top(int* __restrict__ bsum, int nb, int* __restrict__ total)
{
    if (threadIdx.x == 0) {
        int acc = 0;
        for (int i = 0; i < nb; i++) { int v = bsum[i]; bsum[i] = acc; acc += v; }
        *total = acc;
    }
}

__global__ __launch_bounds__(256) void k_scan_out(const int* __restrict__ cnt, int n,
    const int* __restrict__ bsum, int* __restrict__ off, int* __restrict__ cursor)
{
    __shared__ int s[256];
    int t = threadIdx.x;
    int base = blockIdx.x * 1024;
    int v[4]; int a = 0;
    #pragma unroll
    for (int j = 0; j < 4; j++) { int i = base + t * 4 + j; v[j] = (i < n) ? cnt[i] : 0; a += v[j]; }
    s[t] = a; __syncthreads();
    for (int o = 1; o < 256; o <<= 1) {
        int x = (t >= o) ? s[t - o] : 0;
        __syncthreads();
        s[t] += x;
        __syncthreads();
    }
    int excl = (t == 0) ? 0 : s[t - 1];
    int b = bsum[blockIdx.x] + excl;
    #pragma unroll
    for (int j = 0; j < 4; j++) {
        int i = base + t * 4 + j;
        if (i < n) { off[i] = b; cursor[i] = b; }
        b += v[j];
    }
}

__global__ __launch_bounds__(256) void k_fill2(const int* __restrict__ src1, const int* __restrict__ dst1,
    const int* __restrict__ src2, const int* __restrict__ dst2,
    int E1, int L1, int E2, int L2, int NR,
    int* __restrict__ cursor, int* __restrict__ sorted)
{
    int i = blockIdx.x * 256 + threadIdx.x;
    int T1 = E1 + L1, T = T1 + E2 + L2;
    if (i >= T) return;
    int s, d;
    if (i < T1) {
        if (i < E1) { s = src1[i]; d = dst1[i]; } else { s = d = i - E1; }
    } else {
        int k = i - T1;
        if (k < E2) { s = src2[k]; d = NR + dst2[k]; } else { s = k - E2; d = NR + (k - E2); }
    }
    int p = atomicAdd(&cursor[d], 1);
    sorted[p] = s;
}

// ---------------- K_agg: per-dst softmax + bf16 gather-aggregate (wave/dst) -------
// mode 0 (GAT1): a_d_out[d] = advd[d] + cb + (agg . vd2)   [bias folded into cb]
// mode 1 (GAT2): out_final[d*C..] = agg + bias
__global__ __launch_bounds__(256) void k_agg(const int* __restrict__ off, const int* __restrict__ sorted,
    const float* __restrict__ a_s, const float* __restrict__ a_d,
    const u16* __restrict__ hs16, int NR, int mode,
    const float* __restrict__ advd, const float* __restrict__ bias,
    const float* __restrict__ vd2, const float* __restrict__ cb,
    float* __restrict__ a_d_out, float* __restrict__ out_final)
{
    int wave = threadIdx.x >> 6, lane = threadIdx.x & 63;
    int d = blockIdx.x * 4 + wave;
    if (d >= NR) return;
    int beg = off[d], end = off[d + 1];
    float ad0 = a_d[d * 2 + 0], ad1 = a_d[d * 2 + 1];
    float den0 = 0.f, den1 = 0.f;
    for (int j = beg + lane; j < end; j += 64) {
        int s = sorted[j];
        float e0 = a_s[s * 2 + 0] + ad0;
        float e1 = a_s[s * 2 + 1] + ad1;
        e0 = (e0 >= 0.f) ? e0 : 0.2f * e0;
        e1 = (e1 >= 0.f) ? e1 : 0.2f * e1;
        den0 += __expf(e0); den1 += __expf(e1);
    }
    #pragma unroll
    for (int o = 32; o; o >>= 1) { den0 += __shfl_down(den0, o); den1 += __shfl_down(den1, o); }
    den0 = __shfl(den0, 0); den1 = __shfl(den1, 0);
    int head = lane >> 5, j1 = lane & 31;
    float adh = head ? ad1 : ad0;
    float inv = 1.f / ((head ? den1 : den0) + 1e-16f);
    float a0 = 0.f, a1 = 0.f, a2 = 0.f, a3 = 0.f;
    for (int j = beg; j < end; j++) {
        int s = sorted[j];
        float e = a_s[s * 2 + head] + adh;
        e = (e >= 0.f) ? e : 0.2f * e;
        float wgt = __expf(e) * inv;
        const u16* hrow = hs16 + (size_t)s * HC + head * C;
        uint2 g = *(const uint2*)(hrow + 4 * j1);
        a0 += wgt * bfbits2f(g.x & 0xFFFFu);
        a1 += wgt * __uint_as_float(g.x & 0xFFFF0000u);
        a2 += wgt * bfbits2f(g.y & 0xFFFFu);
        a3 += wgt * __uint_as_float(g.y & 0xFFFF0000u);
    }
    // combine heads across half-waves (lane ^ 32)
    float o0 = __shfl(a0, lane ^ 32);
    float o1 = __shfl(a1, lane ^ 32);
    float o2 = __shfl(a2, lane ^ 32);
    float o3 = __shfl(a3, lane ^ 32);
    if (mode == 1) {
        if (lane < 32) {
            float4 bb = ((const float4*)bias)[j1];
            float4 o;
            o.x = 0.5f * (a0 + o0) + bb.x;
            o.y = 0.5f * (a1 + o1) + bb.y;
            o.z = 0.5f * (a2 + o2) + bb.z;
            o.w = 0.5f * (a3 + o3) + bb.w;
            ((float4*)(out_final + (size_t)d * C))[j1] = o;
        }
    } else {
        float s0 = 0.f, s1 = 0.f;
        if (lane < 32) {
            float v[4];
            v[0] = 0.5f * (a0 + o0); v[1] = 0.5f * (a1 + o1);
            v[2] = 0.5f * (a2 + o2); v[3] = 0.5f * (a3 + o3);
            #pragma unroll
            for (int i = 0; i < 4; i++) {
                float2 vv = ((const float2*)vd2)[4 * j1 + i];
                s0 += v[i] * vv.x; s1 += v[i] * vv.y;
            }
        }
        #pragma unroll
        for (int o = 32; o; o >>= 1) { s0 += __shfl_down(s0, o); s1 += __shfl_down(s1, o); }
        if (lane == 0) {
            a_d_out[d * 2 + 0] = advd[d * 2 + 0] + cb[0] + s0;
            a_d_out[d * 2 + 1] = advd[d * 2 + 1] + cb[1] + s1;
        }
    }
}

extern "C" void kernel_launch(void* const* d_in, const int* in_sizes, int n_in,
                              void* d_out, int out_size, void* d_ws, size_t ws_size,
                              hipStream_t stream) {
    const int*   user_ids       = (const int*)d_in[0];
    const int*   ingredient_ids = (const int*)d_in[1];
    const float* recipe_x       = (const float*)d_in[2];
    const int*   ing_src        = (const int*)d_in[3];
    const int*   ing_dst        = (const int*)d_in[4];
    const int*   ub_src         = (const int*)d_in[5];
    const int*   ub_dst         = (const int*)d_in[6];
    const float* user_table     = (const float*)d_in[7];
    const float* ing_table      = (const float*)d_in[8];
    const float* W_rl           = (const float*)d_in[9];
    const float* bn_gamma       = (const float*)d_in[11];
    const float* bn_beta        = (const float*)d_in[12];
    const float* g1_ws          = (const float*)d_in[13];
    const float* g1_wd          = (const float*)d_in[14];
    const float* g1_as          = (const float*)d_in[15];
    const float* g1_ad          = (const float*)d_in[16];
    const float* g1_b           = (const float*)d_in[17];
    const float* g2_ws          = (const float*)d_in[18];
    const float* g2_wd          = (const float*)d_in[19];
    const float* g2_as          = (const float*)d_in[20];
    const float* g2_ad          = (const float*)d_in[21];
    const float* g2_b           = (const float*)d_in[22];

    int NU = in_sizes[0];
    int NI = in_sizes[1];
    int NR = in_sizes[2] / DIN;
    int E1 = in_sizes[3];
    int E2 = in_sizes[5];
    int Nmax = (NI > NU) ? NI : NU;
    int L1 = (NI < NR) ? NI : NR;
    int L2 = (NU < NR) ? NU : NR;
    int Etot = E1 + L1 + E2 + L2;
    int n2 = 2 * NR;
    int nb2 = (n2 + 1023) / 1024;

    char* w = (char*)d_ws;
    u16*   hs16  = (u16*)w;    w += (size_t)Nmax * HC * 2;
    float* a_s   = (float*)w;  w += (size_t)Nmax * 2 * 4;
    float* a_d   = (float*)w;  w += (size_t)NR * 2 * 4;
    float* advd  = (float*)w;  w += (size_t)NR * 2 * 4;
    float* stats = (float*)w;  w += 1280 * 4;
    int*   cnt   = (int*)w;    w += (size_t)n2 * 4;
    int*   off   = (int*)w;    w += (size_t)(n2 + 1) * 4;
    int*   cursor= (int*)w;    w += (size_t)n2 * 4;
    int*   bsum  = (int*)w;    w += (size_t)(nb2 + 1) * 4;
    int*   sorted= (int*)w;    w += (size_t)Etot * 4;

    hipMemsetAsync(stats, 0, 420 * 4, stream);
    hipMemsetAsync(cnt, 0, (size_t)n2 * 4, stream);

    // BN stats + folded constants
    k_stats<<<(NR + 255) / 256, 256, 0, stream>>>(recipe_x, NR, stats);
    k_precomp<<<1, 256, 0, stream>>>(stats, W_rl, bn_gamma, bn_beta,
                                     g1_wd, g1_ad, g2_wd, g2_ad, g1_b, 1.0f / NR);
    // combined CSR build (both graphs)
    k_hist2<<<(Etot + 255) / 256, 256, 0, stream>>>(ing_dst, ub_dst, E1, L1, E2, L2, NR, cnt);
    k_scan_bsum<<<nb2, 256, 0, stream>>>(cnt, n2, bsum);
    k_scan_top<<<1, 64, 0, stream>>>(bsum, nb2, off + n2);
    k_scan_out<<<nb2, 256, 0, stream>>>(cnt, n2, bsum, off, cursor);
    k_fill2<<<(Etot + 255) / 256, 256, 0, stream>>>(ing_src, ing_dst, ub_src, ub_dst,
                                                    E1, L1, E2, L2, NR, cursor, sorted);
    // GAT1
    k_r0<<<(NR + 15) / 16, 256, 0, stream>>>(recipe_x, W_rl, stats, NR, a_d, advd);
    k_hs<<<(NI + 15) / 16, 256, 0, stream>>>(ing_table, ingredient_ids, g1_ws, g1_as, NI, 0, hs16, a_s);
    k_agg<<<(NR + 3) / 4, 256, 0, stream>>>(off, sorted, a_s, a_d, hs16, NR, 0,
                                            advd, g1_b, stats + 932, stats + 1188,
                                            a_d, (float*)nullptr);
    // GAT2
    k_hs<<<(NU + 15) / 16, 256, 0, stream>>>(user_table, user_ids, g2_ws, g2_as, NU, 1, hs16, a_s);
    k_agg<<<(NR + 3) / 4, 256, 0, stream>>>(off + NR, sorted, a_s, a_d, hs16, NR, 1,
                                            (const float*)nullptr, g2_b, (const float*)nullptr,
                                            (const float*)nullptr,
                                            (float*)nullptr, (float*)d_out);
}

// Round 5
// 686.753 us; speedup vs baseline: 1.7276x; 1.0848x over previous
//
#include <hip/hip_runtime.h>
#include <hip/hip_bf16.h>
#include <math.h>

#define DIN 20
#define C 128
#define HC 256

typedef unsigned short u16;

__device__ __forceinline__ float bfbits2f(unsigned int lo16) {
    return __uint_as_float(lo16 << 16);
}
__device__ __forceinline__ u16 f2bf_rne(float f) {
    unsigned int b = __float_as_uint(f);
    return (u16)((b + 0x7FFFu + ((b >> 16) & 1u)) >> 16);
}

// ---------------- K1: BN stats (second moment 20x20 + column sums) ----------------
__global__ __launch_bounds__(256) void k_stats(const float* __restrict__ x, int NR,
                                               float* __restrict__ stats)
{
    __shared__ float L[256][DIN];
    int t = threadIdx.x;
    int r = blockIdx.x * 256 + t;
    if (r < NR) {
        #pragma unroll
        for (int k = 0; k < DIN; k++) L[t][k] = x[r * DIN + k];
    } else {
        #pragma unroll
        for (int k = 0; k < DIN; k++) L[t][k] = 0.f;
    }
    __syncthreads();
    if (t < 210) {
        int p = 0, q = t;
        while (q >= DIN - p) { q -= (DIN - p); p++; }
        q += p;
        float acc = 0.f;
        for (int rr = 0; rr < 256; rr++) acc += L[rr][p] * L[rr][q];
        atomicAdd(&stats[p * DIN + q], acc);
        if (p != q) atomicAdd(&stats[q * DIN + p], acc);
    } else if (t < 230) {
        int k = t - 210;
        float acc = 0.f;
        for (int rr = 0; rr < 256; rr++) acc += L[rr][k];
        atomicAdd(&stats[400 + k], acc);
    }
}

// ---------------- K2: fold BN; vd1/vd2 = w_d @ att_d; cb = b1 . vd2 ---------------
// stats: [420..547]=BN scale, [548..675]=BN shift, [676..931]=vd1[k*2+h],
//        [932..1187]=vd2[k*2+h], [1188..1189]=cb[h]
__global__ __launch_bounds__(256) void k_precomp(float* __restrict__ stats,
    const float* __restrict__ W,
    const float* __restrict__ gamma, const float* __restrict__ beta,
    const float* __restrict__ g1_wd, const float* __restrict__ g1_ad,
    const float* __restrict__ g2_wd, const float* __restrict__ g2_ad,
    const float* __restrict__ g1b, float invN)
{
    int t = threadIdx.x;
    if (t < C) {
        float w[DIN];
        #pragma unroll
        for (int k = 0; k < DIN; k++) w[k] = W[k * C + t];
        float mb = 0.f;
        #pragma unroll
        for (int k = 0; k < DIN; k++) mb += stats[400 + k] * invN * w[k];
        float e2 = 0.f;
        for (int p = 0; p < DIN; p++) {
            float acc2 = 0.f;
            for (int q = 0; q < DIN; q++) acc2 += stats[p * DIN + q] * w[q];
            e2 += w[p] * acc2;
        }
        e2 *= invN;
        float var = e2 - mb * mb;
        float s = gamma[t] * rsqrtf(var + 1e-5f);
        stats[420 + t] = s;
        stats[548 + t] = beta[t] - s * mb;   // b_rl cancels inside BN
    }
    {
        int k = t >> 1, h = t & 1;
        float a1 = 0.f, a2 = 0.f;
        for (int c = 0; c < C; c++) {
            a1 += g1_wd[k * HC + h * C + c] * g1_ad[h * C + c];
            a2 += g2_wd[k * HC + h * C + c] * g2_ad[h * C + c];
        }
        stats[676 + k * 2 + h] = a1;
        stats[932 + k * 2 + h] = a2;
    }
    __syncthreads();
    if (t < 2) {
        float cb = 0.f;
        for (int k = 0; k < C; k++) cb += g1b[k] * stats[932 + k * 2 + t];
        stats[1188 + t] = cb;
    }
}

// ---------------- K3: BN(x@W) folded -> a_d1 = r0.vd1, advd = r0.vd2 --------------
__global__ __launch_bounds__(256) void k_r0(const float* __restrict__ x, const float* __restrict__ W,
    const float* __restrict__ stats, int NR,
    float* __restrict__ a_d, float* __restrict__ advd)
{
    __shared__ float xr[16 * DIN];
    __shared__ float red[16];
    int t = threadIdx.x;
    int rowBase = blockIdx.x * 16;
    for (int i = t; i < 16 * DIN; i += 256) {
        int gi = rowBase * DIN + i;
        xr[i] = (gi < NR * DIN) ? x[gi] : 0.f;
    }
    int c = t & 127;
    int half = t >> 7;
    int wv = t >> 6;
    float w[DIN];
    #pragma unroll
    for (int k = 0; k < DIN; k++) w[k] = W[k * C + c];
    float s  = stats[420 + c], sh = stats[548 + c];
    float v10 = stats[676 + c * 2 + 0], v11 = stats[676 + c * 2 + 1];
    float v20 = stats[932 + c * 2 + 0], v21 = stats[932 + c * 2 + 1];
    __syncthreads();
    for (int p = 0; p < 8; p++) {
        int lr = 2 * p + half;
        float dot = 0.f;
        #pragma unroll
        for (int k = 0; k < DIN; k++) dot += w[k] * xr[lr * DIN + k];
        float val = s * dot + sh;
        float p0 = val * v10, p1 = val * v11, q0 = val * v20, q1 = val * v21;
        #pragma unroll
        for (int o = 32; o; o >>= 1) {
            p0 += __shfl_down(p0, o); p1 += __shfl_down(p1, o);
            q0 += __shfl_down(q0, o); q1 += __shfl_down(q1, o);
        }
        if ((t & 63) == 0) {
            red[wv * 4 + 0] = p0; red[wv * 4 + 1] = p1;
            red[wv * 4 + 2] = q0; red[wv * 4 + 3] = q1;
        }
        __syncthreads();
        int rowA = rowBase + 2 * p, rowB = rowA + 1;
        if (t == 0 && rowA < NR) {
            a_d[rowA * 2 + 0]  = red[0] + red[4];
            a_d[rowA * 2 + 1]  = red[1] + red[5];
            advd[rowA * 2 + 0] = red[2] + red[6];
            advd[rowA * 2 + 1] = red[3] + red[7];
        }
        if (t == 128 && rowB < NR) {
            a_d[rowB * 2 + 0]  = red[8]  + red[12];
            a_d[rowB * 2 + 1]  = red[9]  + red[13];
            advd[rowB * 2 + 0] = red[10] + red[14];
            advd[rowB * 2 + 1] = red[11] + red[15];
        }
        __syncthreads();
    }
}

// ---------------- K4: hs kernel: gather+GEMM; emits a_s (+psi | +hs16) ------------
// psi[row][h][h'] = hs(row, head h) . vd2[:, h']  (for GAT1 — avoids hs gather)
__global__ __launch_bounds__(256) void k_hs(const float* __restrict__ table,
    const int* __restrict__ ids, const float* __restrict__ ws, const float* __restrict__ att,
    const float* __restrict__ vd2, int Ns, int renorm,
    u16* __restrict__ hs16, float* __restrict__ psi, float* __restrict__ a_s)
{
    __shared__ float A[16 * C];   // 8 KB
    __shared__ float attS[HC];
    __shared__ float red2[4][48];
    int t = threadIdx.x;
    int rowBase = blockIdx.x * 16;
    attS[t] = att[t];
    #pragma unroll
    for (int j = 0; j < 8; j++) {
        int idx = t + 256 * j;
        int r = idx >> 7, cc = idx & 127;
        int row = rowBase + r;
        float v = 0.f;
        if (row < Ns) v = table[(size_t)ids[row] * C + cc];
        A[r * C + cc] = v;
    }
    __syncthreads();
    if (renorm) {
        int wv0 = t >> 6, l = t & 63;
        #pragma unroll
        for (int rr = 0; rr < 4; rr++) {
            int r = wv0 * 4 + rr;
            float v1 = A[r * C + l], v2 = A[r * C + l + 64];
            float ss = v1 * v1 + v2 * v2;
            #pragma unroll
            for (int o = 32; o; o >>= 1) ss += __shfl_down(ss, o);
            ss = __shfl(ss, 0);
            float nn = sqrtf(ss);
            float f = (nn > 1.f) ? 1.f / (nn + 1e-7f) : 1.f;
            A[r * C + l] = v1 * f; A[r * C + l + 64] = v2 * f;
        }
        __syncthreads();
    }
    float acc[16];
    #pragma unroll
    for (int r = 0; r < 16; r++) acc[r] = 0.f;
    const float* wcol = ws + t;
    for (int k4 = 0; k4 < C / 4; k4++) {
        float b0 = wcol[(4 * k4 + 0) * HC];
        float b1 = wcol[(4 * k4 + 1) * HC];
        float b2 = wcol[(4 * k4 + 2) * HC];
        float b3 = wcol[(4 * k4 + 3) * HC];
        #pragma unroll
        for (int r = 0; r < 16; r++) {
            float4 a = *(const float4*)&A[r * C + 4 * k4];
            acc[r] += a.x * b0 + a.y * b1 + a.z * b2 + a.w * b3;
        }
    }
    int wv = t >> 6;
    int c = t & 127;
    float v20 = vd2 ? vd2[c * 2 + 0] : 0.f;
    float v21 = vd2 ? vd2[c * 2 + 1] : 0.f;
    #pragma unroll
    for (int r = 0; r < 16; r++) {
        float p0 = acc[r] * attS[t];
        float p1 = acc[r] * v20;
        float p2 = acc[r] * v21;
        #pragma unroll
        for (int o = 32; o; o >>= 1) {
            p0 += __shfl_down(p0, o);
            p1 += __shfl_down(p1, o);
            p2 += __shfl_down(p2, o);
        }
        if ((t & 63) == 0) {
            red2[wv][r * 3 + 0] = p0;
            red2[wv][r * 3 + 1] = p1;
            red2[wv][r * 3 + 2] = p2;
        }
    }
    __syncthreads();
    if (t < 32) {
        int h = t >> 4, r = t & 15;
        int row = rowBase + r;
        if (row < Ns) {
            a_s[row * 2 + h] = red2[2 * h][r * 3] + red2[2 * h + 1][r * 3];
            if (psi) {
                psi[row * 4 + h * 2 + 0] = red2[2 * h][r * 3 + 1] + red2[2 * h + 1][r * 3 + 1];
                psi[row * 4 + h * 2 + 1] = red2[2 * h][r * 3 + 2] + red2[2 * h + 1][r * 3 + 2];
            }
        }
    }
    if (hs16) {
        #pragma unroll
        for (int r = 0; r < 16; r++) {
            int row = rowBase + r;
            if (row < Ns) hs16[(size_t)row * HC + t] = f2bf_rne(acc[r]);
        }
    }
}

// ---------------- Combined CSR build for both graphs ------------------------------
__global__ __launch_bounds__(256) void k_hist2(const int* __restrict__ dst1, const int* __restrict__ dst2,
    int E1, int L1, int E2, int L2, int NR, int* __restrict__ cnt)
{
    int i = blockIdx.x * 256 + threadIdx.x;
    int T1 = E1 + L1, T = T1 + E2 + L2;
    if (i >= T) return;
    int d;
    if (i < T1) d = (i < E1) ? dst1[i] : (i - E1);
    else { int k = i - T1; d = NR + ((k < E2) ? dst2[k] : (k - E2)); }
    atomicAdd(&cnt[d], 1);
}

__global__ __launch_bounds__(256) void k_scan_bsum(const int* __restrict__ cnt, int n,
                                                   int* __restrict__ bsum)
{
    __shared__ int s[256];
    int t = threadIdx.x;
    int base = blockIdx.x * 1024;
    int a = 0;
    #pragma unroll
    for (int j = 0; j < 4; j++) { int i = base + t * 4 + j; a += (i < n) ? cnt[i] : 0; }
    s[t] = a; __syncthreads();
    for (int off = 128; off; off >>= 1) { if (t < off) s[t] += s[t + off]; __syncthreads(); }
    if (t == 0) bsum[blockIdx.x] = s[0];
}

__global__ void k_scan_top(int* __restrict__ bsum, int nb, int* __restrict__ total)
{
    if (threadIdx.x == 0) {
        int acc = 0;
        for (int i = 0; i < nb; i++) { int v = bsum[i]; bsum[i] = acc; acc += v; }
        *total = acc;
    }
}

__global__ __launch_bounds__(256) void k_scan_out(const int* __restrict__ cnt, int n,
    const int* __restrict__ bsum, int* __restrict__ off, int* __restrict__ cursor)
{
    __shared__ int s[256];
    int t = threadIdx.x;
    int base = blockIdx.x * 1024;
    int v[4]; int a = 0;
    #pragma unroll
    for (int j = 0; j < 4; j++) { int i = base + t * 4 + j; v[j] = (i < n) ? cnt[i] : 0; a += v[j]; }
    s[t] = a; __syncthreads();
    for (int o = 1; o < 256; o <<= 1) {
        int x = (t >= o) ? s[t - o] : 0;
        __syncthreads();
        s[t] += x;
        __syncthreads();
    }
    int excl = (t == 0) ? 0 : s[t - 1];
    int b = bsum[blockIdx.x] + excl;
    #pragma unroll
    for (int j = 0; j < 4; j++) {
        int i = base + t * 4 + j;
        if (i < n) { off[i] = b; cursor[i] = b; }
        b += v[j];
    }
}

__global__ __launch_bounds__(256) void k_fill2(const int* __restrict__ src1, const int* __restrict__ dst1,
    const int* __restrict__ src2, const int* __restrict__ dst2,
    int E1, int L1, int E2, int L2, int NR,
    int* __restrict__ cursor, int* __restrict__ sorted)
{
    int i = blockIdx.x * 256 + threadIdx.x;
    int T1 = E1 + L1, T = T1 + E2 + L2;
    if (i >= T) return;
    int s, d;
    if (i < T1) {
        if (i < E1) { s = src1[i]; d = dst1[i]; } else { s = d = i - E1; }
    } else {
        int k = i - T1;
        if (k < E2) { s = src2[k]; d = NR + dst2[k]; } else { s = k - E2; d = NR + (k - E2); }
    }
    int p = atomicAdd(&cursor[d], 1);
    sorted[p] = s;
}

// ---------------- GAT1 agg: 16B-per-edge psi aggregation (wave per dst) -----------
// a_d_out[d][h'] = advd[d][h'] + cb[h'] + 0.5 * sum_h ( sum_j w_hj psi[s_j][h][h'] ) / W_h
__global__ __launch_bounds__(256) void k_agg_lin(const int* __restrict__ off, const int* __restrict__ sorted,
    const float* __restrict__ a_s, const float* __restrict__ psi,
    const float* __restrict__ a_d, const float* __restrict__ advd,
    const float* __restrict__ cb, int NR, float* __restrict__ a_d_out)
{
    int wave = threadIdx.x >> 6, lane = threadIdx.x & 63;
    int d = blockIdx.x * 4 + wave;
    if (d >= NR) return;
    int beg = off[d], end = off[d + 1];
    float ad0 = a_d[d * 2 + 0], ad1 = a_d[d * 2 + 1];
    float w0s = 0.f, w1s = 0.f, a00 = 0.f, a01 = 0.f, a10 = 0.f, a11 = 0.f;
    for (int j = beg + lane; j < end; j += 64) {
        int s = sorted[j];
        float2 as = ((const float2*)a_s)[s];
        float e0 = as.x + ad0; e0 = (e0 >= 0.f) ? e0 : 0.2f * e0;
        float e1 = as.y + ad1; e1 = (e1 >= 0.f) ? e1 : 0.2f * e1;
        float x0 = __expf(e0), x1 = __expf(e1);
        float4 p = ((const float4*)psi)[s];
        w0s += x0; w1s += x1;
        a00 += x0 * p.x; a01 += x0 * p.y;
        a10 += x1 * p.z; a11 += x1 * p.w;
    }
    #pragma unroll
    for (int o = 32; o; o >>= 1) {
        w0s += __shfl_down(w0s, o); w1s += __shfl_down(w1s, o);
        a00 += __shfl_down(a00, o); a01 += __shfl_down(a01, o);
        a10 += __shfl_down(a10, o); a11 += __shfl_down(a11, o);
    }
    if (lane == 0) {
        float inv0 = 1.f / (w0s + 1e-16f), inv1 = 1.f / (w1s + 1e-16f);
        a_d_out[d * 2 + 0] = advd[d * 2 + 0] + cb[0] + 0.5f * (a00 * inv0 + a10 * inv1);
        a_d_out[d * 2 + 1] = advd[d * 2 + 1] + cb[1] + 0.5f * (a01 * inv0 + a11 * inv1);
    }
}

// ---------------- GAT2 agg: fused single-pass bf16 gather (wave per dst) ----------
// lanes: slot=lane>>5 (edge pair), head=(lane>>4)&1, cg=lane&15 (8 channels, 16B)
__global__ __launch_bounds__(256) void k_agg_gather(const int* __restrict__ off, const int* __restrict__ sorted,
    const float* __restrict__ a_s, const float* __restrict__ a_d,
    const u16* __restrict__ hs16, const float* __restrict__ bias,
    int NR, float* __restrict__ out)
{
    int wave = threadIdx.x >> 6, lane = threadIdx.x & 63;
    int d = blockIdx.x * 4 + wave;
    if (d >= NR) return;
    int beg = off[d], end = off[d + 1];
    int slot = lane >> 5, head = (lane >> 4) & 1, cg = lane & 15;
    float adh = a_d[d * 2 + head];
    float wsum = 0.f;
    float acc[8];
    #pragma unroll
    for (int k = 0; k < 8; k++) acc[k] = 0.f;

    for (int base = beg; base < end; base += 64) {
        int rem = end - base; if (rem > 64) rem = 64;
        int pidx = base + ((lane < rem) ? lane : (rem - 1));
        int sp = sorted[pidx];
        float2 ap = ((const float2*)a_s)[sp];
        for (int i = 0; i < rem; i += 2) {
            int eo = i + slot;
            bool valid = eo < rem;
            int lsrc = valid ? eo : (rem - 1);
            int s   = __shfl(sp, lsrc);
            float asx = __shfl(ap.x, lsrc);
            float asy = __shfl(ap.y, lsrc);
            float as = head ? asy : asx;
            float ee = as + adh; ee = (ee >= 0.f) ? ee : 0.2f * ee;
            float w = valid ? __expf(ee) : 0.f;
            wsum += w;
            const u16* hrow = hs16 + (size_t)s * HC + (head << 7) + (cg << 3);
            uint4 g = *(const uint4*)hrow;
            acc[0] += w * bfbits2f(g.x & 0xFFFFu);
            acc[1] += w * __uint_as_float(g.x & 0xFFFF0000u);
            acc[2] += w * bfbits2f(g.y & 0xFFFFu);
            acc[3] += w * __uint_as_float(g.y & 0xFFFF0000u);
            acc[4] += w * bfbits2f(g.z & 0xFFFFu);
            acc[5] += w * __uint_as_float(g.z & 0xFFFF0000u);
            acc[6] += w * bfbits2f(g.w & 0xFFFFu);
            acc[7] += w * __uint_as_float(g.w & 0xFFFF0000u);
        }
    }
    // combine slots (lane ^ 32)
    wsum += __shfl(wsum, lane ^ 32);
    #pragma unroll
    for (int k = 0; k < 8; k++) acc[k] += __shfl(acc[k], lane ^ 32);
    float inv = 1.f / (wsum + 1e-16f);
    #pragma unroll
    for (int k = 0; k < 8; k++) acc[k] *= inv;
    // combine heads (lane ^ 16), mean
    #pragma unroll
    for (int k = 0; k < 8; k++) acc[k] = 0.5f * (acc[k] + __shfl(acc[k], lane ^ 16));
    if (lane < 16) {
        const float4* b4 = (const float4*)bias;
        float4 bb0 = b4[cg * 2], bb1 = b4[cg * 2 + 1];
        float4 o0, o1;
        o0.x = acc[0] + bb0.x; o0.y = acc[1] + bb0.y; o0.z = acc[2] + bb0.z; o0.w = acc[3] + bb0.w;
        o1.x = acc[4] + bb1.x; o1.y = acc[5] + bb1.y; o1.z = acc[6] + bb1.z; o1.w = acc[7] + bb1.w;
        float4* op = (float4*)(out + (size_t)d * C + (cg << 3));
        op[0] = o0; op[1] = o1;
    }
}

extern "C" void kernel_launch(void* const* d_in, const int* in_sizes, int n_in,
                              void* d_out, int out_size, void* d_ws, size_t ws_size,
                              hipStream_t stream) {
    const int*   user_ids       = (const int*)d_in[0];
    const int*   ingredient_ids = (const int*)d_in[1];
    const float* recipe_x       = (const float*)d_in[2];
    const int*   ing_src        = (const int*)d_in[3];
    const int*   ing_dst        = (const int*)d_in[4];
    const int*   ub_src         = (const int*)d_in[5];
    const int*   ub_dst         = (const int*)d_in[6];
    const float* user_table     = (const float*)d_in[7];
    const float* ing_table      = (const float*)d_in[8];
    const float* W_rl           = (const float*)d_in[9];
    const float* bn_gamma       = (const float*)d_in[11];
    const float* bn_beta        = (const float*)d_in[12];
    const float* g1_ws          = (const float*)d_in[13];
    const float* g1_wd          = (const float*)d_in[14];
    const float* g1_as          = (const float*)d_in[15];
    const float* g1_ad          = (const float*)d_in[16];
    const float* g1_b           = (const float*)d_in[17];
    const float* g2_ws          = (const float*)d_in[18];
    const float* g2_wd          = (const float*)d_in[19];
    const float* g2_as          = (const float*)d_in[20];
    const float* g2_ad          = (const float*)d_in[21];
    const float* g2_b           = (const float*)d_in[22];

    int NU = in_sizes[0];
    int NI = in_sizes[1];
    int NR = in_sizes[2] / DIN;
    int E1 = in_sizes[3];
    int E2 = in_sizes[5];
    int Nmax = (NI > NU) ? NI : NU;
    int L1 = (NI < NR) ? NI : NR;
    int L2 = (NU < NR) ? NU : NR;
    int Etot = E1 + L1 + E2 + L2;
    int n2 = 2 * NR;
    int nb2 = (n2 + 1023) / 1024;

    char* w = (char*)d_ws;
    u16*   hs16  = (u16*)w;    w += (size_t)Nmax * HC * 2;
    float* a_s   = (float*)w;  w += (size_t)Nmax * 2 * 4;
    float* psi   = (float*)w;  w += (size_t)NI * 4 * 4;
    float* a_d   = (float*)w;  w += (size_t)NR * 2 * 4;
    float* advd  = (float*)w;  w += (size_t)NR * 2 * 4;
    float* stats = (float*)w;  w += 1280 * 4;
    int*   cnt   = (int*)w;    w += (size_t)n2 * 4;
    int*   off   = (int*)w;    w += (size_t)(n2 + 1) * 4;
    int*   cursor= (int*)w;    w += (size_t)n2 * 4;
    int*   bsum  = (int*)w;    w += (size_t)(nb2 + 1) * 4;
    int*   sorted= (int*)w;    w += (size_t)Etot * 4;

    hipMemsetAsync(stats, 0, 420 * 4, stream);
    hipMemsetAsync(cnt, 0, (size_t)n2 * 4, stream);

    // BN stats + folded constants
    k_stats<<<(NR + 255) / 256, 256, 0, stream>>>(recipe_x, NR, stats);
    k_precomp<<<1, 256, 0, stream>>>(stats, W_rl, bn_gamma, bn_beta,
                                     g1_wd, g1_ad, g2_wd, g2_ad, g1_b, 1.0f / NR);
    // combined CSR build (both graphs)
    k_hist2<<<(Etot + 255) / 256, 256, 0, stream>>>(ing_dst, ub_dst, E1, L1, E2, L2, NR, cnt);
    k_scan_bsum<<<nb2, 256, 0, stream>>>(cnt, n2, bsum);
    k_scan_top<<<1, 64, 0, stream>>>(bsum, nb2, off + n2);
    k_scan_out<<<nb2, 256, 0, stream>>>(cnt, n2, bsum, off, cursor);
    k_fill2<<<(Etot + 255) / 256, 256, 0, stream>>>(ing_src, ing_dst, ub_src, ub_dst,
                                                    E1, L1, E2, L2, NR, cursor, sorted);
    // GAT1: psi-based (no hs materialization for ingredients)
    k_r0<<<(NR + 15) / 16, 256, 0, stream>>>(recipe_x, W_rl, stats, NR, a_d, advd);
    k_hs<<<(NI + 15) / 16, 256, 0, stream>>>(ing_table, ingredient_ids, g1_ws, g1_as,
                                             stats + 932, NI, 0,
                                             (u16*)nullptr, psi, a_s);
    k_agg_lin<<<(NR + 3) / 4, 256, 0, stream>>>(off, sorted, a_s, psi, a_d, advd,
                                                stats + 1188, NR, a_d);
    // GAT2: bf16 hs gather
    k_hs<<<(NU + 15) / 16, 256, 0, stream>>>(user_table, user_ids, g2_ws, g2_as,
                                             (const float*)nullptr, NU, 1,
                                             hs16, (float*)nullptr, a_s);
    k_agg_gather<<<(NR + 3) / 4, 256, 0, stream>>>(off + NR, sorted, a_s, a_d, hs16,
                                                   g2_b, NR, (float*)d_out);
}

// Round 6
// 556.272 us; speedup vs baseline: 2.1328x; 1.2346x over previous
//
#include <hip/hip_runtime.h>
#include <hip/hip_bf16.h>
#include <math.h>

#define DIN 20
#define C 128
#define HC 256

typedef unsigned short u16;
typedef __bf16 bf16x8 __attribute__((ext_vector_type(8)));
typedef float f32x4 __attribute__((ext_vector_type(4)));

__device__ __forceinline__ float bfbits2f(unsigned int lo16) {
    return __uint_as_float(lo16 << 16);
}
__device__ __forceinline__ u16 f2bf_rne(float f) {
    unsigned int b = __float_as_uint(f);
    return (u16)((b + 0x7FFFu + ((b >> 16) & 1u)) >> 16);
}

// ---------------- K1: BN stats (second moment 20x20 + column sums) ----------------
__global__ __launch_bounds__(256) void k_stats(const float* __restrict__ x, int NR,
                                               float* __restrict__ stats)
{
    __shared__ float L[256][DIN];
    int t = threadIdx.x;
    int r = blockIdx.x * 256 + t;
    if (r < NR) {
        #pragma unroll
        for (int k = 0; k < DIN; k++) L[t][k] = x[r * DIN + k];
    } else {
        #pragma unroll
        for (int k = 0; k < DIN; k++) L[t][k] = 0.f;
    }
    __syncthreads();
    if (t < 210) {
        int p = 0, q = t;
        while (q >= DIN - p) { q -= (DIN - p); p++; }
        q += p;
        float acc = 0.f;
        for (int rr = 0; rr < 256; rr++) acc += L[rr][p] * L[rr][q];
        atomicAdd(&stats[p * DIN + q], acc);
        if (p != q) atomicAdd(&stats[q * DIN + p], acc);
    } else if (t < 230) {
        int k = t - 210;
        float acc = 0.f;
        for (int rr = 0; rr < 256; rr++) acc += L[rr][k];
        atomicAdd(&stats[400 + k], acc);
    }
}

// ---------------- K2: fold BN; vd1/vd2; u1/u2; T; cb ------------------------------
// stats: [420..547]=BN scale, [548..675]=BN shift, [676..931]=vd1[k*2+h],
//        [932..1187]=vd2[c*2+h'], [1188..1189]=cb[h'],
//        [1200..1455]=u1[k*2+h], [1456..1711]=u2[k*2+h],
//        [1712..2223]=T[k*4+h*2+h']
__global__ __launch_bounds__(256) void k_precomp(float* __restrict__ stats,
    const float* __restrict__ W,
    const float* __restrict__ gamma, const float* __restrict__ beta,
    const float* __restrict__ g1_wd, const float* __restrict__ g1_ad,
    const float* __restrict__ g2_wd, const float* __restrict__ g2_ad,
    const float* __restrict__ g1_ws, const float* __restrict__ g1_as,
    const float* __restrict__ g2_ws, const float* __restrict__ g2_as,
    const float* __restrict__ g1b, float invN)
{
    int t = threadIdx.x;
    if (t < C) {
        float w[DIN];
        #pragma unroll
        for (int k = 0; k < DIN; k++) w[k] = W[k * C + t];
        float mb = 0.f;
        #pragma unroll
        for (int k = 0; k < DIN; k++) mb += stats[400 + k] * invN * w[k];
        float e2 = 0.f;
        for (int p = 0; p < DIN; p++) {
            float acc2 = 0.f;
            for (int q = 0; q < DIN; q++) acc2 += stats[p * DIN + q] * w[q];
            e2 += w[p] * acc2;
        }
        e2 *= invN;
        float var = e2 - mb * mb;
        float s = gamma[t] * rsqrtf(var + 1e-5f);
        stats[420 + t] = s;
        stats[548 + t] = beta[t] - s * mb;   // b_rl cancels inside BN
    }
    {
        int k = t >> 1, h = t & 1;
        float a1 = 0.f, a2 = 0.f, s1 = 0.f, s2 = 0.f;
        for (int c = 0; c < C; c++) {
            a1 += g1_wd[k * HC + h * C + c] * g1_ad[h * C + c];
            a2 += g2_wd[k * HC + h * C + c] * g2_ad[h * C + c];
            s1 += g1_ws[k * HC + h * C + c] * g1_as[h * C + c];
            s2 += g2_ws[k * HC + h * C + c] * g2_as[h * C + c];
        }
        stats[676 + t] = a1;
        stats[932 + t] = a2;
        stats[1200 + t] = s1;
        stats[1456 + t] = s2;
    }
    __syncthreads();
    {
        // T[k][h][h'] = sum_c g1_ws[k][h*128+c] * vd2[c][h']
        int k = t >> 1, h = t & 1;
        float t0 = 0.f, t1 = 0.f;
        for (int c = 0; c < C; c++) {
            float wv = g1_ws[k * HC + h * C + c];
            t0 += wv * stats[932 + c * 2 + 0];
            t1 += wv * stats[932 + c * 2 + 1];
        }
        stats[1712 + t * 2 + 0] = t0;
        stats[1712 + t * 2 + 1] = t1;
    }
    if (t < 2) {
        float cb = 0.f;
        for (int k = 0; k < C; k++) cb += g1b[k] * stats[932 + k * 2 + t];
        stats[1188 + t] = cb;
    }
}

// ---------------- K_pack: g2_ws -> bf16 MFMA B-fragment layout --------------------
// frag id f = nt*4+kb; element: lane l, j: B[kb*32+(l>>4)*8+j][nt*16+(l&15)]
__global__ __launch_bounds__(256) void k_pack(const float* __restrict__ ws, u16* __restrict__ p)
{
    int idx0 = (blockIdx.x * 256 + threadIdx.x) * 4;
    #pragma unroll
    for (int i = 0; i < 4; i++) {
        int flat = idx0 + i;           // [nt(16)][kb(4)][lane(64)][j(8)]
        int j = flat & 7;
        int lane = (flat >> 3) & 63;
        int kb = (flat >> 9) & 3;
        int nt = flat >> 11;
        int k = kb * 32 + (lane >> 4) * 8 + j;
        int n = nt * 16 + (lane & 15);
        p[flat] = f2bf_rne(ws[k * HC + n]);
    }
}

// ---------------- K3: BN(x@W) folded -> a_d1 = r0.vd1, advd = r0.vd2 --------------
__global__ __launch_bounds__(256) void k_r0(const float* __restrict__ x, const float* __restrict__ W,
    const float* __restrict__ stats, int NR,
    float* __restrict__ a_d, float* __restrict__ advd)
{
    __shared__ float xr[16 * DIN];
    __shared__ float red[16];
    int t = threadIdx.x;
    int rowBase = blockIdx.x * 16;
    for (int i = t; i < 16 * DIN; i += 256) {
        int gi = rowBase * DIN + i;
        xr[i] = (gi < NR * DIN) ? x[gi] : 0.f;
    }
    int c = t & 127;
    int half = t >> 7;
    int wv = t >> 6;
    float w[DIN];
    #pragma unroll
    for (int k = 0; k < DIN; k++) w[k] = W[k * C + c];
    float s  = stats[420 + c], sh = stats[548 + c];
    float v10 = stats[676 + c * 2 + 0], v11 = stats[676 + c * 2 + 1];
    float v20 = stats[932 + c * 2 + 0], v21 = stats[932 + c * 2 + 1];
    __syncthreads();
    for (int p = 0; p < 8; p++) {
        int lr = 2 * p + half;
        float dot = 0.f;
        #pragma unroll
        for (int k = 0; k < DIN; k++) dot += w[k] * xr[lr * DIN + k];
        float val = s * dot + sh;
        float p0 = val * v10, p1 = val * v11, q0 = val * v20, q1 = val * v21;
        #pragma unroll
        for (int o = 32; o; o >>= 1) {
            p0 += __shfl_down(p0, o); p1 += __shfl_down(p1, o);
            q0 += __shfl_down(q0, o); q1 += __shfl_down(q1, o);
        }
        if ((t & 63) == 0) {
            red[wv * 4 + 0] = p0; red[wv * 4 + 1] = p1;
            red[wv * 4 + 2] = q0; red[wv * 4 + 3] = q1;
        }
        __syncthreads();
        int rowA = rowBase + 2 * p, rowB = rowA + 1;
        if (t == 0 && rowA < NR) {
            a_d[rowA * 2 + 0]  = red[0] + red[4];
            a_d[rowA * 2 + 1]  = red[1] + red[5];
            advd[rowA * 2 + 0] = red[2] + red[6];
            advd[rowA * 2 + 1] = red[3] + red[7];
        }
        if (t == 128 && rowB < NR) {
            a_d[rowB * 2 + 0]  = red[8]  + red[12];
            a_d[rowB * 2 + 1]  = red[9]  + red[13];
            advd[rowB * 2 + 0] = red[10] + red[14];
            advd[rowB * 2 + 1] = red[11] + red[15];
        }
        __syncthreads();
    }
}

// ---------------- K_ing: ingredient path = pure gather + 6 dots per row -----------
// a_s[row][h] = x . u1[:,h]; psi[row][h*2+h'] = x . T[:,h*2+h']
__global__ __launch_bounds__(256) void k_ing(const float* __restrict__ table,
    const int* __restrict__ ids, const float* __restrict__ stats,
    int Ns, float* __restrict__ a_s, float* __restrict__ psi)
{
    __shared__ float u1s[256];
    __shared__ float Ts[512];
    int t = threadIdx.x;
    u1s[t] = stats[1200 + t];
    Ts[t] = stats[1712 + t];
    Ts[256 + t] = stats[1968 + t];
    __syncthreads();
    int r = t >> 3, cg = t & 7;
    int row = blockIdx.x * 32 + r;
    float as0 = 0.f, as1 = 0.f, p00 = 0.f, p01 = 0.f, p10 = 0.f, p11 = 0.f;
    if (row < Ns) {
        const float* xp = table + (size_t)ids[row] * C + cg * 16;
        #pragma unroll
        for (int q = 0; q < 4; q++) {
            float4 v = ((const float4*)xp)[q];
            float xv[4] = {v.x, v.y, v.z, v.w};
            #pragma unroll
            for (int jj = 0; jj < 4; jj++) {
                int k = cg * 16 + q * 4 + jj;
                float xx = xv[jj];
                as0 += xx * u1s[k * 2 + 0];
                as1 += xx * u1s[k * 2 + 1];
                p00 += xx * Ts[k * 4 + 0];
                p01 += xx * Ts[k * 4 + 1];
                p10 += xx * Ts[k * 4 + 2];
                p11 += xx * Ts[k * 4 + 3];
            }
        }
    }
    #pragma unroll
    for (int m = 1; m <= 4; m <<= 1) {
        as0 += __shfl_xor(as0, m); as1 += __shfl_xor(as1, m);
        p00 += __shfl_xor(p00, m); p01 += __shfl_xor(p01, m);
        p10 += __shfl_xor(p10, m); p11 += __shfl_xor(p11, m);
    }
    if (cg == 0 && row < Ns) {
        ((float2*)a_s)[row] = make_float2(as0, as1);
        float4 pv; pv.x = p00; pv.y = p01; pv.z = p10; pv.w = p11;
        ((float4*)psi)[row] = pv;
    }
}

// ---------------- K_hs_mfma: user hs GEMM via MFMA + a_s via u2 -------------------
// 32 rows/block, A staged bf16 in LDS (stride 136), B from packed global.
__global__ __launch_bounds__(256) void k_hs_mfma(const float* __restrict__ table,
    const int* __restrict__ ids, const u16* __restrict__ wsp,
    const float* __restrict__ stats, int Ns,
    u16* __restrict__ hs16, float* __restrict__ a_s)
{
    __shared__ __align__(16) u16 A[32 * 136];
    __shared__ float u2s[256];
    int t = threadIdx.x;
    u2s[t] = stats[1456 + t];
    int rowBase = blockIdx.x * 32;
    int r = t >> 3, cg = t & 7;
    int row = rowBase + r;
    // gather 16 f32, renorm, a_s dot, bf16 -> LDS
    float xv[16];
    if (row < Ns) {
        const float* xp = table + (size_t)ids[row] * C + cg * 16;
        #pragma unroll
        for (int q = 0; q < 4; q++) {
            float4 v = ((const float4*)xp)[q];
            xv[q * 4 + 0] = v.x; xv[q * 4 + 1] = v.y;
            xv[q * 4 + 2] = v.z; xv[q * 4 + 3] = v.w;
        }
    } else {
        #pragma unroll
        for (int q = 0; q < 16; q++) xv[q] = 0.f;
    }
    float ss = 0.f;
    #pragma unroll
    for (int q = 0; q < 16; q++) ss += xv[q] * xv[q];
    #pragma unroll
    for (int m = 1; m <= 4; m <<= 1) ss += __shfl_xor(ss, m);
    float nn = sqrtf(ss);
    float f = (nn > 1.f) ? 1.f / (nn + 1e-7f) : 1.f;
    float as0 = 0.f, as1 = 0.f;
    #pragma unroll
    for (int q = 0; q < 16; q++) {
        xv[q] *= f;
        int k = cg * 16 + q;
        as0 += xv[q] * u2s[k * 2 + 0];
        as1 += xv[q] * u2s[k * 2 + 1];
    }
    #pragma unroll
    for (int m = 1; m <= 4; m <<= 1) {
        as0 += __shfl_xor(as0, m); as1 += __shfl_xor(as1, m);
    }
    if (cg == 0 && row < Ns) ((float2*)a_s)[row] = make_float2(as0, as1);
    {
        union { u16 h[16]; uint4 u4[2]; } pk;
        #pragma unroll
        for (int q = 0; q < 16; q++) pk.h[q] = f2bf_rne(xv[q]);
        uint4* dst = (uint4*)&A[r * 136 + cg * 16];
        dst[0] = pk.u4[0];
        dst[1] = pk.u4[1];
    }
    __syncthreads();
    // MFMA: wave w handles n-tiles w*4..w*4+3, m-tiles 0,1
    int w = t >> 6, l = t & 63;
    int m15 = l & 15, q4 = l >> 4;
    bf16x8 afrag[2][4];
    #pragma unroll
    for (int mt = 0; mt < 2; mt++)
        #pragma unroll
        for (int kb = 0; kb < 4; kb++)
            afrag[mt][kb] = *(const bf16x8*)&A[(mt * 16 + m15) * 136 + kb * 32 + q4 * 8];
    f32x4 acc[2][4];
    #pragma unroll
    for (int mt = 0; mt < 2; mt++)
        #pragma unroll
        for (int i = 0; i < 4; i++) acc[mt][i] = (f32x4){0.f, 0.f, 0.f, 0.f};
    #pragma unroll
    for (int kb = 0; kb < 4; kb++) {
        #pragma unroll
        for (int i = 0; i < 4; i++) {
            int nt = w * 4 + i;
            bf16x8 bfrag = *(const bf16x8*)&wsp[((nt * 4 + kb) * 64 + l) * 8];
            acc[0][i] = __builtin_amdgcn_mfma_f32_16x16x32_bf16(afrag[0][kb], bfrag, acc[0][i], 0, 0, 0);
            acc[1][i] = __builtin_amdgcn_mfma_f32_16x16x32_bf16(afrag[1][kb], bfrag, acc[1][i], 0, 0, 0);
        }
    }
    // store: D[row = mt*16 + q4*4 + rr][col = nt*16 + m15]
    #pragma unroll
    for (int mt = 0; mt < 2; mt++) {
        #pragma unroll
        for (int i = 0; i < 4; i++) {
            int col = (w * 4 + i) * 16 + m15;
            #pragma unroll
            for (int rr = 0; rr < 4; rr++) {
                int rw = rowBase + mt * 16 + q4 * 4 + rr;
                if (rw < Ns) hs16[(size_t)rw * HC + col] = f2bf_rne(acc[mt][i][rr]);
            }
        }
    }
}

// ---------------- Combined CSR build for both graphs ------------------------------
__global__ __launch_bounds__(256) void k_hist2(const int* __restrict__ dst1, const int* __restrict__ dst2,
    int E1, int L1, int E2, int L2, int NR, int* __restrict__ cnt)
{
    int i = blockIdx.x * 256 + threadIdx.x;
    int T1 = E1 + L1, T = T1 + E2 + L2;
    if (i >= T) return;
    int d;
    if (i < T1) d = (i < E1) ? dst1[i] : (i - E1);
    else { int k = i - T1; d = NR + ((k < E2) ? dst2[k] : (k - E2)); }
    atomicAdd(&cnt[d], 1);
}

__global__ __launch_bounds__(256) void k_scan_bsum(const int* __restrict__ cnt, int n,
                                                   int* __restrict__ bsum)
{
    __shared__ int s[256];
    int t = threadIdx.x;
    int base = blockIdx.x * 1024;
    int a = 0;
    #pragma unroll
    for (int j = 0; j < 4; j++) { int i = base + t * 4 + j; a += (i < n) ? cnt[i] : 0; }
    s[t] = a; __syncthreads();
    for (int off = 128; off; off >>= 1) { if (t < off) s[t] += s[t + off]; __syncthreads(); }
    if (t == 0) bsum[blockIdx.x] = s[0];
}

__global__ void k_scan_top(int* __restrict__ bsum, int nb, int* __restrict__ total)
{
    if (threadIdx.x == 0) {
        int acc = 0;
        for (int i = 0; i < nb; i++) { int v = bsum[i]; bsum[i] = acc; acc += v; }
        *total = acc;
    }
}

__global__ __launch_bounds__(256) void k_scan_out(const int* __restrict__ cnt, int n,
    const int* __restrict__ bsum, int* __restrict__ off, int* __restrict__ cursor)
{
    __shared__ int s[256];
    int t = threadIdx.x;
    int base = blockIdx.x * 1024;
    int v[4]; int a = 0;
    #pragma unroll
    for (int j = 0; j < 4; j++) { int i = base + t * 4 + j; v[j] = (i < n) ? cnt[i] : 0; a += v[j]; }
    s[t] = a; __syncthreads();
    for (int o = 1; o < 256; o <<= 1) {
        int x = (t >= o) ? s[t - o] : 0;
        __syncthreads();
        s[t] += x;
        __syncthreads();
    }
    int excl = (t == 0) ? 0 : s[t - 1];
    int b = bsum[blockIdx.x] + excl;
    #pragma unroll
    for (int j = 0; j < 4; j++) {
        int i = base + t * 4 + j;
        if (i < n) { off[i] = b; cursor[i] = b; }
        b += v[j];
    }
}

__global__ __launch_bounds__(256) void k_fill2(const int* __restrict__ src1, const int* __restrict__ dst1,
    const int* __restrict__ src2, const int* __restrict__ dst2,
    int E1, int L1, int E2, int L2, int NR,
    int* __restrict__ cursor, int* __restrict__ sorted)
{
    int i = blockIdx.x * 256 + threadIdx.x;
    int T1 = E1 + L1, T = T1 + E2 + L2;
    if (i >= T) return;
    int s, d;
    if (i < T1) {
        if (i < E1) { s = src1[i]; d = dst1[i]; } else { s = d = i - E1; }
    } else {
        int k = i - T1;
        if (k < E2) { s = src2[k]; d = NR + dst2[k]; } else { s = k - E2; d = NR + (k - E2); }
    }
    int p = atomicAdd(&cursor[d], 1);
    sorted[p] = s;
}

// ---------------- GAT1 agg: 16B-per-edge psi aggregation (wave per dst) -----------
__global__ __launch_bounds__(256) void k_agg_lin(const int* __restrict__ off, const int* __restrict__ sorted,
    const float* __restrict__ a_s, const float* __restrict__ psi,
    const float* __restrict__ a_d, const float* __restrict__ advd,
    const float* __restrict__ cb, int NR, float* __restrict__ a_d_out)
{
    int wave = threadIdx.x >> 6, lane = threadIdx.x & 63;
    int d = blockIdx.x * 4 + wave;
    if (d >= NR) return;
    int beg = off[d], end = off[d + 1];
    float ad0 = a_d[d * 2 + 0], ad1 = a_d[d * 2 + 1];
    float w0s = 0.f, w1s = 0.f, a00 = 0.f, a01 = 0.f, a10 = 0.f, a11 = 0.f;
    for (int j = beg + lane; j < end; j += 64) {
        int s = sorted[j];
        float2 as = ((const float2*)a_s)[s];
        float e0 = as.x + ad0; e0 = (e0 >= 0.f) ? e0 : 0.2f * e0;
        float e1 = as.y + ad1; e1 = (e1 >= 0.f) ? e1 : 0.2f * e1;
        float x0 = __expf(e0), x1 = __expf(e1);
        float4 p = ((const float4*)psi)[s];
        w0s += x0; w1s += x1;
        a00 += x0 * p.x; a01 += x0 * p.y;
        a10 += x1 * p.z; a11 += x1 * p.w;
    }
    #pragma unroll
    for (int o = 32; o; o >>= 1) {
        w0s += __shfl_down(w0s, o); w1s += __shfl_down(w1s, o);
        a00 += __shfl_down(a00, o); a01 += __shfl_down(a01, o);
        a10 += __shfl_down(a10, o); a11 += __shfl_down(a11, o);
    }
    if (lane == 0) {
        float inv0 = 1.f / (w0s + 1e-16f), inv1 = 1.f / (w1s + 1e-16f);
        a_d_out[d * 2 + 0] = advd[d * 2 + 0] + cb[0] + 0.5f * (a00 * inv0 + a10 * inv1);
        a_d_out[d * 2 + 1] = advd[d * 2 + 1] + cb[1] + 0.5f * (a01 * inv0 + a11 * inv1);
    }
}

// ---------------- GAT2 agg: fused single-pass bf16 gather (wave per dst) ----------
__global__ __launch_bounds__(256) void k_agg_gather(const int* __restrict__ off, const int* __restrict__ sorted,
    const float* __restrict__ a_s, const float* __restrict__ a_d,
    const u16* __restrict__ hs16, const float* __restrict__ bias,
    int NR, float* __restrict__ out)
{
    int wave = threadIdx.x >> 6, lane = threadIdx.x & 63;
    int d = blockIdx.x * 4 + wave;
    if (d >= NR) return;
    int beg = off[d], end = off[d + 1];
    int slot = lane >> 5, head = (lane >> 4) & 1, cg = lane & 15;
    float adh = a_d[d * 2 + head];
    float wsum = 0.f;
    float acc[8];
    #pragma unroll
    for (int k = 0; k < 8; k++) acc[k] = 0.f;

    for (int base = beg; base < end; base += 64) {
        int rem = end - base; if (rem > 64) rem = 64;
        int pidx = base + ((lane < rem) ? lane : (rem - 1));
        int sp = sorted[pidx];
        float2 ap = ((const float2*)a_s)[sp];
        for (int i = 0; i < rem; i += 2) {
            int eo = i + slot;
            bool valid = eo < rem;
            int lsrc = valid ? eo : (rem - 1);
            int s   = __shfl(sp, lsrc);
            float asx = __shfl(ap.x, lsrc);
            float asy = __shfl(ap.y, lsrc);
            float as = head ? asy : asx;
            float ee = as + adh; ee = (ee >= 0.f) ? ee : 0.2f * ee;
            float w = valid ? __expf(ee) : 0.f;
            wsum += w;
            const u16* hrow = hs16 + (size_t)s * HC + (head << 7) + (cg << 3);
            uint4 g = *(const uint4*)hrow;
            acc[0] += w * bfbits2f(g.x & 0xFFFFu);
            acc[1] += w * __uint_as_float(g.x & 0xFFFF0000u);
            acc[2] += w * bfbits2f(g.y & 0xFFFFu);
            acc[3] += w * __uint_as_float(g.y & 0xFFFF0000u);
            acc[4] += w * bfbits2f(g.z & 0xFFFFu);
            acc[5] += w * __uint_as_float(g.z & 0xFFFF0000u);
            acc[6] += w * bfbits2f(g.w & 0xFFFFu);
            acc[7] += w * __uint_as_float(g.w & 0xFFFF0000u);
        }
    }
    wsum += __shfl(wsum, lane ^ 32);
    #pragma unroll
    for (int k = 0; k < 8; k++) acc[k] += __shfl(acc[k], lane ^ 32);
    float inv = 1.f / (wsum + 1e-16f);
    #pragma unroll
    for (int k = 0; k < 8; k++) acc[k] *= inv;
    #pragma unroll
    for (int k = 0; k < 8; k++) acc[k] = 0.5f * (acc[k] + __shfl(acc[k], lane ^ 16));
    if (lane < 16) {
        const float4* b4 = (const float4*)bias;
        float4 bb0 = b4[cg * 2], bb1 = b4[cg * 2 + 1];
        float4 o0, o1;
        o0.x = acc[0] + bb0.x; o0.y = acc[1] + bb0.y; o0.z = acc[2] + bb0.z; o0.w = acc[3] + bb0.w;
        o1.x = acc[4] + bb1.x; o1.y = acc[5] + bb1.y; o1.z = acc[6] + bb1.z; o1.w = acc[7] + bb1.w;
        float4* op = (float4*)(out + (size_t)d * C + (cg << 3));
        op[0] = o0; op[1] = o1;
    }
}

extern "C" void kernel_launch(void* const* d_in, const int* in_sizes, int n_in,
                              void* d_out, int out_size, void* d_ws, size_t ws_size,
                              hipStream_t stream) {
    const int*   user_ids       = (const int*)d_in[0];
    const int*   ingredient_ids = (const int*)d_in[1];
    const float* recipe_x       = (const float*)d_in[2];
    const int*   ing_src        = (const int*)d_in[3];
    const int*   ing_dst        = (const int*)d_in[4];
    const int*   ub_src         = (const int*)d_in[5];
    const int*   ub_dst         = (const int*)d_in[6];
    const float* user_table     = (const float*)d_in[7];
    const float* ing_table      = (const float*)d_in[8];
    const float* W_rl           = (const float*)d_in[9];
    const float* bn_gamma       = (const float*)d_in[11];
    const float* bn_beta        = (const float*)d_in[12];
    const float* g1_ws          = (const float*)d_in[13];
    const float* g1_wd          = (const float*)d_in[14];
    const float* g1_as          = (const float*)d_in[15];
    const float* g1_ad          = (const float*)d_in[16];
    const float* g1_b           = (const float*)d_in[17];
    const float* g2_ws          = (const float*)d_in[18];
    const float* g2_wd          = (const float*)d_in[19];
    const float* g2_as          = (const float*)d_in[20];
    const float* g2_ad          = (const float*)d_in[21];
    const float* g2_b           = (const float*)d_in[22];

    int NU = in_sizes[0];
    int NI = in_sizes[1];
    int NR = in_sizes[2] / DIN;
    int E1 = in_sizes[3];
    int E2 = in_sizes[5];
    int Nmax = (NI > NU) ? NI : NU;
    int L1 = (NI < NR) ? NI : NR;
    int L2 = (NU < NR) ? NU : NR;
    int Etot = E1 + L1 + E2 + L2;
    int n2 = 2 * NR;
    int nb2 = (n2 + 1023) / 1024;

    char* w = (char*)d_ws;
    u16*   hs16  = (u16*)w;    w += (size_t)Nmax * HC * 2;
    float* a_s   = (float*)w;  w += (size_t)Nmax * 2 * 4;
    float* psi   = (float*)w;  w += (size_t)NI * 4 * 4;
    float* a_d   = (float*)w;  w += (size_t)NR * 2 * 4;
    float* advd  = (float*)w;  w += (size_t)NR * 2 * 4;
    float* stats = (float*)w;  w += 2304 * 4;
    u16*   wsp   = (u16*)w;    w += 32768 * 2;
    int*   cnt   = (int*)w;    w += (size_t)n2 * 4;
    int*   off   = (int*)w;    w += (size_t)(n2 + 1) * 4;
    int*   cursor= (int*)w;    w += (size_t)n2 * 4;
    int*   bsum  = (int*)w;    w += (size_t)(nb2 + 1) * 4;
    int*   sorted= (int*)w;    w += (size_t)Etot * 4;

    hipMemsetAsync(stats, 0, 420 * 4, stream);
    hipMemsetAsync(cnt, 0, (size_t)n2 * 4, stream);

    // BN stats + folded constants + B-pack
    k_stats<<<(NR + 255) / 256, 256, 0, stream>>>(recipe_x, NR, stats);
    k_precomp<<<1, 256, 0, stream>>>(stats, W_rl, bn_gamma, bn_beta,
                                     g1_wd, g1_ad, g2_wd, g2_ad,
                                     g1_ws, g1_as, g2_ws, g2_as, g1_b, 1.0f / NR);
    k_pack<<<32, 256, 0, stream>>>(g2_ws, wsp);
    // combined CSR build (both graphs)
    k_hist2<<<(Etot + 255) / 256, 256, 0, stream>>>(ing_dst, ub_dst, E1, L1, E2, L2, NR, cnt);
    k_scan_bsum<<<nb2, 256, 0, stream>>>(cnt, n2, bsum);
    k_scan_top<<<1, 64, 0, stream>>>(bsum, nb2, off + n2);
    k_scan_out<<<nb2, 256, 0, stream>>>(cnt, n2, bsum, off, cursor);
    k_fill2<<<(Etot + 255) / 256, 256, 0, stream>>>(ing_src, ing_dst, ub_src, ub_dst,
                                                    E1, L1, E2, L2, NR, cursor, sorted);
    // GAT1: psi-based, no GEMM
    k_r0<<<(NR + 15) / 16, 256, 0, stream>>>(recipe_x, W_rl, stats, NR, a_d, advd);
    k_ing<<<(NI + 31) / 32, 256, 0, stream>>>(ing_table, ingredient_ids, stats, NI, a_s, psi);
    k_agg_lin<<<(NR + 3) / 4, 256, 0, stream>>>(off, sorted, a_s, psi, a_d, advd,
                                                stats + 1188, NR, a_d);
    // GAT2: MFMA hs GEMM + bf16 gather
    k_hs_mfma<<<(NU + 31) / 32, 256, 0, stream>>>(user_table, user_ids, wsp, stats, NU,
                                                  hs16, a_s);
    k_agg_gather<<<(NR + 3) / 4, 256, 0, stream>>>(off + NR, sorted, a_s, a_d, hs16,
                                                   g2_b, NR, (float*)d_out);
}

// Round 7
// 475.408 us; speedup vs baseline: 2.4956x; 1.1701x over previous
//
#include <hip/hip_runtime.h>
#include <hip/hip_bf16.h>
#include <math.h>

#define DIN 20
#define C 128
#define HC 256
#define EB1 8192
#define EB2 4096
#define MAXNB 400

typedef unsigned short u16;
typedef unsigned int u32;
typedef unsigned long long u64;
typedef __bf16 bf16x8 __attribute__((ext_vector_type(8)));
typedef float f32x4 __attribute__((ext_vector_type(4)));

__device__ __forceinline__ float bfbits2f(unsigned int lo16) {
    return __uint_as_float(lo16 << 16);
}
__device__ __forceinline__ u16 f2bf_rne(float f) {
    unsigned int b = __float_as_uint(f);
    return (u16)((b + 0x7FFFu + ((b >> 16) & 1u)) >> 16);
}

// exclusive scan of cnt[0..511] -> off[0..511] using 256 threads; tmp[256]
__device__ __forceinline__ void scan512(u32* cnt, u32* off, u32* tmp) {
    int t = threadIdx.x;
    u32 a = cnt[2 * t], b = cnt[2 * t + 1];
    u32 s = a + b;
    tmp[t] = s;
    __syncthreads();
    for (int o = 1; o < 256; o <<= 1) {
        u32 v = (t >= o) ? tmp[t - o] : 0u;
        __syncthreads();
        tmp[t] += v;
        __syncthreads();
    }
    u32 excl = tmp[t] - s;
    off[2 * t] = excl;
    off[2 * t + 1] = excl + a;
    __syncthreads();
}

// ---------------- K1: BN stats (second moment 20x20 + column sums) ----------------
__global__ __launch_bounds__(256) void k_stats(const float* __restrict__ x, int NR,
                                               float* __restrict__ stats)
{
    __shared__ float L[256][DIN];
    int t = threadIdx.x;
    int r = blockIdx.x * 256 + t;
    if (r < NR) {
        #pragma unroll
        for (int k = 0; k < DIN; k++) L[t][k] = x[r * DIN + k];
    } else {
        #pragma unroll
        for (int k = 0; k < DIN; k++) L[t][k] = 0.f;
    }
    __syncthreads();
    if (t < 210) {
        int p = 0, q = t;
        while (q >= DIN - p) { q -= (DIN - p); p++; }
        q += p;
        float acc = 0.f;
        for (int rr = 0; rr < 256; rr++) acc += L[rr][p] * L[rr][q];
        atomicAdd(&stats[p * DIN + q], acc);
        if (p != q) atomicAdd(&stats[q * DIN + p], acc);
    } else if (t < 230) {
        int k = t - 210;
        float acc = 0.f;
        for (int rr = 0; rr < 256; rr++) acc += L[rr][k];
        atomicAdd(&stats[400 + k], acc);
    }
}

// ---------------- K2: fold BN; vd1/vd2; u1/u2; T; cb ------------------------------
// stats: [420..547]=BN scale, [548..675]=BN shift, [676..931]=vd1[k*2+h],
//        [932..1187]=vd2[c*2+h'], [1188..1189]=cb[h'],
//        [1200..1455]=u1[k*2+h], [1456..1711]=u2[k*2+h], [1712..2223]=T[k*4+h*2+h']
__global__ __launch_bounds__(256) void k_precomp(float* __restrict__ stats,
    const float* __restrict__ W,
    const float* __restrict__ gamma, const float* __restrict__ beta,
    const float* __restrict__ g1_wd, const float* __restrict__ g1_ad,
    const float* __restrict__ g2_wd, const float* __restrict__ g2_ad,
    const float* __restrict__ g1_ws, const float* __restrict__ g1_as,
    const float* __restrict__ g2_ws, const float* __restrict__ g2_as,
    const float* __restrict__ g1b, float invN)
{
    int t = threadIdx.x;
    if (t < C) {
        float w[DIN];
        #pragma unroll
        for (int k = 0; k < DIN; k++) w[k] = W[k * C + t];
        float mb = 0.f;
        #pragma unroll
        for (int k = 0; k < DIN; k++) mb += stats[400 + k] * invN * w[k];
        float e2 = 0.f;
        for (int p = 0; p < DIN; p++) {
            float acc2 = 0.f;
            for (int q = 0; q < DIN; q++) acc2 += stats[p * DIN + q] * w[q];
            e2 += w[p] * acc2;
        }
        e2 *= invN;
        float var = e2 - mb * mb;
        float s = gamma[t] * rsqrtf(var + 1e-5f);
        stats[420 + t] = s;
        stats[548 + t] = beta[t] - s * mb;   // b_rl cancels inside BN
    }
    {
        int k = t >> 1, h = t & 1;
        float a1 = 0.f, a2 = 0.f, s1 = 0.f, s2 = 0.f;
        for (int c = 0; c < C; c++) {
            a1 += g1_wd[k * HC + h * C + c] * g1_ad[h * C + c];
            a2 += g2_wd[k * HC + h * C + c] * g2_ad[h * C + c];
            s1 += g1_ws[k * HC + h * C + c] * g1_as[h * C + c];
            s2 += g2_ws[k * HC + h * C + c] * g2_as[h * C + c];
        }
        stats[676 + t] = a1;
        stats[932 + t] = a2;
        stats[1200 + t] = s1;
        stats[1456 + t] = s2;
    }
    __syncthreads();
    {
        int k = t >> 1, h = t & 1;
        float t0 = 0.f, t1 = 0.f;
        for (int c = 0; c < C; c++) {
            float wv = g1_ws[k * HC + h * C + c];
            t0 += wv * stats[932 + c * 2 + 0];
            t1 += wv * stats[932 + c * 2 + 1];
        }
        stats[1712 + t * 2 + 0] = t0;
        stats[1712 + t * 2 + 1] = t1;
    }
    if (t < 2) {
        float cb = 0.f;
        for (int k = 0; k < C; k++) cb += g1b[k] * stats[932 + k * 2 + t];
        stats[1188 + t] = cb;
    }
}

// ---------------- K_pack: g2_ws -> bf16 MFMA B-fragment layout --------------------
__global__ __launch_bounds__(256) void k_pack(const float* __restrict__ ws, u16* __restrict__ p)
{
    int idx0 = (blockIdx.x * 256 + threadIdx.x) * 4;
    #pragma unroll
    for (int i = 0; i < 4; i++) {
        int flat = idx0 + i;           // [nt(16)][kb(4)][lane(64)][j(8)]
        int j = flat & 7;
        int lane = (flat >> 3) & 63;
        int kb = (flat >> 9) & 3;
        int nt = flat >> 11;
        int k = kb * 32 + (lane >> 4) * 8 + j;
        int n = nt * 16 + (lane & 15);
        p[flat] = f2bf_rne(ws[k * HC + n]);
    }
}

// ---------------- K3: BN(x@W) folded -> a_d1 = r0.vd1, advd = r0.vd2 --------------
__global__ __launch_bounds__(256) void k_r0(const float* __restrict__ x, const float* __restrict__ W,
    const float* __restrict__ stats, int NR,
    float* __restrict__ a_d, float* __restrict__ advd)
{
    __shared__ float xr[16 * DIN];
    __shared__ float red[16];
    int t = threadIdx.x;
    int rowBase = blockIdx.x * 16;
    for (int i = t; i < 16 * DIN; i += 256) {
        int gi = rowBase * DIN + i;
        xr[i] = (gi < NR * DIN) ? x[gi] : 0.f;
    }
    int c = t & 127;
    int half = t >> 7;
    int wv = t >> 6;
    float w[DIN];
    #pragma unroll
    for (int k = 0; k < DIN; k++) w[k] = W[k * C + c];
    float s  = stats[420 + c], sh = stats[548 + c];
    float v10 = stats[676 + c * 2 + 0], v11 = stats[676 + c * 2 + 1];
    float v20 = stats[932 + c * 2 + 0], v21 = stats[932 + c * 2 + 1];
    __syncthreads();
    for (int p = 0; p < 8; p++) {
        int lr = 2 * p + half;
        float dot = 0.f;
        #pragma unroll
        for (int k = 0; k < DIN; k++) dot += w[k] * xr[lr * DIN + k];
        float val = s * dot + sh;
        float p0 = val * v10, p1 = val * v11, q0 = val * v20, q1 = val * v21;
        #pragma unroll
        for (int o = 32; o; o >>= 1) {
            p0 += __shfl_down(p0, o); p1 += __shfl_down(p1, o);
            q0 += __shfl_down(q0, o); q1 += __shfl_down(q1, o);
        }
        if ((t & 63) == 0) {
            red[wv * 4 + 0] = p0; red[wv * 4 + 1] = p1;
            red[wv * 4 + 2] = q0; red[wv * 4 + 3] = q1;
        }
        __syncthreads();
        int rowA = rowBase + 2 * p, rowB = rowA + 1;
        if (t == 0 && rowA < NR) {
            a_d[rowA * 2 + 0]  = red[0] + red[4];
            a_d[rowA * 2 + 1]  = red[1] + red[5];
            advd[rowA * 2 + 0] = red[2] + red[6];
            advd[rowA * 2 + 1] = red[3] + red[7];
        }
        if (t == 128 && rowB < NR) {
            a_d[rowB * 2 + 0]  = red[8]  + red[12];
            a_d[rowB * 2 + 1]  = red[9]  + red[13];
            advd[rowB * 2 + 0] = red[10] + red[14];
            advd[rowB * 2 + 1] = red[11] + red[15];
        }
        __syncthreads();
    }
}

// ---------------- K_ing: ingredient path = pure gather + 6 dots per row -----------
__global__ __launch_bounds__(256) void k_ing(const float* __restrict__ table,
    const int* __restrict__ ids, const float* __restrict__ stats,
    int Ns, float* __restrict__ a_s, float* __restrict__ psi)
{
    __shared__ float u1s[256];
    __shared__ float Ts[512];
    int t = threadIdx.x;
    u1s[t] = stats[1200 + t];
    Ts[t] = stats[1712 + t];
    Ts[256 + t] = stats[1968 + t];
    __syncthreads();
    int r = t >> 3, cg = t & 7;
    int row = blockIdx.x * 32 + r;
    float as0 = 0.f, as1 = 0.f, p00 = 0.f, p01 = 0.f, p10 = 0.f, p11 = 0.f;
    if (row < Ns) {
        const float* xp = table + (size_t)ids[row] * C + cg * 16;
        #pragma unroll
        for (int q = 0; q < 4; q++) {
            float4 v = ((const float4*)xp)[q];
            float xv[4] = {v.x, v.y, v.z, v.w};
            #pragma unroll
            for (int jj = 0; jj < 4; jj++) {
                int k = cg * 16 + q * 4 + jj;
                float xx = xv[jj];
                as0 += xx * u1s[k * 2 + 0];
                as1 += xx * u1s[k * 2 + 1];
                p00 += xx * Ts[k * 4 + 0];
                p01 += xx * Ts[k * 4 + 1];
                p10 += xx * Ts[k * 4 + 2];
                p11 += xx * Ts[k * 4 + 3];
            }
        }
    }
    #pragma unroll
    for (int m = 1; m <= 4; m <<= 1) {
        as0 += __shfl_xor(as0, m); as1 += __shfl_xor(as1, m);
        p00 += __shfl_xor(p00, m); p01 += __shfl_xor(p01, m);
        p10 += __shfl_xor(p10, m); p11 += __shfl_xor(p11, m);
    }
    if (cg == 0 && row < Ns) {
        ((float2*)a_s)[row] = make_float2(as0, as1);
        float4 pv; pv.x = p00; pv.y = p01; pv.z = p10; pv.w = p11;
        ((float4*)psi)[row] = pv;
    }
}

// ---------------- K_hs_mfma: user hs GEMM via MFMA + a_s via u2 -------------------
__global__ __launch_bounds__(256) void k_hs_mfma(const float* __restrict__ table,
    const int* __restrict__ ids, const u16* __restrict__ wsp,
    const float* __restrict__ stats, int Ns,
    u16* __restrict__ hs16, float* __restrict__ a_s)
{
    __shared__ __align__(16) u16 A[32 * 136];
    __shared__ float u2s[256];
    int t = threadIdx.x;
    u2s[t] = stats[1456 + t];
    int rowBase = blockIdx.x * 32;
    int r = t >> 3, cg = t & 7;
    int row = rowBase + r;
    float xv[16];
    if (row < Ns) {
        const float* xp = table + (size_t)ids[row] * C + cg * 16;
        #pragma unroll
        for (int q = 0; q < 4; q++) {
            float4 v = ((const float4*)xp)[q];
            xv[q * 4 + 0] = v.x; xv[q * 4 + 1] = v.y;
            xv[q * 4 + 2] = v.z; xv[q * 4 + 3] = v.w;
        }
    } else {
        #pragma unroll
        for (int q = 0; q < 16; q++) xv[q] = 0.f;
    }
    float ss = 0.f;
    #pragma unroll
    for (int q = 0; q < 16; q++) ss += xv[q] * xv[q];
    #pragma unroll
    for (int m = 1; m <= 4; m <<= 1) ss += __shfl_xor(ss, m);
    float nn = sqrtf(ss);
    float f = (nn > 1.f) ? 1.f / (nn + 1e-7f) : 1.f;
    float as0 = 0.f, as1 = 0.f;
    #pragma unroll
    for (int q = 0; q < 16; q++) {
        xv[q] *= f;
        int k = cg * 16 + q;
        as0 += xv[q] * u2s[k * 2 + 0];
        as1 += xv[q] * u2s[k * 2 + 1];
    }
    #pragma unroll
    for (int m = 1; m <= 4; m <<= 1) {
        as0 += __shfl_xor(as0, m); as1 += __shfl_xor(as1, m);
    }
    if (cg == 0 && row < Ns) ((float2*)a_s)[row] = make_float2(as0, as1);
    {
        union { u16 h[16]; uint4 u4[2]; } pk;
        #pragma unroll
        for (int q = 0; q < 16; q++) pk.h[q] = f2bf_rne(xv[q]);
        uint4* dst = (uint4*)&A[r * 136 + cg * 16];
        dst[0] = pk.u4[0];
        dst[1] = pk.u4[1];
    }
    __syncthreads();
    int w = t >> 6, l = t & 63;
    int m15 = l & 15, q4 = l >> 4;
    bf16x8 afrag[2][4];
    #pragma unroll
    for (int mt = 0; mt < 2; mt++)
        #pragma unroll
        for (int kb = 0; kb < 4; kb++)
            afrag[mt][kb] = *(const bf16x8*)&A[(mt * 16 + m15) * 136 + kb * 32 + q4 * 8];
    f32x4 acc[2][4];
    #pragma unroll
    for (int mt = 0; mt < 2; mt++)
        #pragma unroll
        for (int i = 0; i < 4; i++) acc[mt][i] = (f32x4){0.f, 0.f, 0.f, 0.f};
    #pragma unroll
    for (int kb = 0; kb < 4; kb++) {
        #pragma unroll
        for (int i = 0; i < 4; i++) {
            int nt = w * 4 + i;
            bf16x8 bfrag = *(const bf16x8*)&wsp[((nt * 4 + kb) * 64 + l) * 8];
            acc[0][i] = __builtin_amdgcn_mfma_f32_16x16x32_bf16(afrag[0][kb], bfrag, acc[0][i], 0, 0, 0);
            acc[1][i] = __builtin_amdgcn_mfma_f32_16x16x32_bf16(afrag[1][kb], bfrag, acc[1][i], 0, 0, 0);
        }
    }
    #pragma unroll
    for (int mt = 0; mt < 2; mt++) {
        #pragma unroll
        for (int i = 0; i < 4; i++) {
            int col = (w * 4 + i) * 16 + m15;
            #pragma unroll
            for (int rr = 0; rr < 4; rr++) {
                int rw = rowBase + mt * 16 + q4 * 4 + rr;
                if (rw < Ns) hs16[(size_t)rw * HC + col] = f2bf_rne(acc[mt][i][rr]);
            }
        }
    }
}

// ================= Bucketed CSR build =================
// key space [0, 2*NR): graph1 key=d, graph2 key=NR+d. bucket = key>>9.

__device__ __forceinline__ void edge_at(int i, const int* s1, const int* d1,
    const int* s2, const int* d2, int E1, int T1, int E2, int NR,
    int& s, int& key)
{
    if (i < T1) {
        if (i < E1) { s = s1[i]; key = d1[i]; }
        else        { s = i - E1; key = i - E1; }
    } else {
        int k = i - T1;
        if (k < E2) { s = s2[k]; key = NR + d2[k]; }
        else        { s = k - E2; key = NR + (k - E2); }
    }
}

// A1: per-block LDS bucket histogram -> global bucketCnt
__global__ __launch_bounds__(256) void kA1(const int* __restrict__ src1, const int* __restrict__ dst1,
    const int* __restrict__ src2, const int* __restrict__ dst2,
    int E1, int L1, int E2, int L2, int NR, int NB, u32* __restrict__ bucketCnt)
{
    __shared__ u32 cnt[MAXNB];
    int t = threadIdx.x;
    for (int i = t; i < NB; i += 256) cnt[i] = 0;
    __syncthreads();
    int T1 = E1 + L1, T = T1 + E2 + L2;
    int base = blockIdx.x * EB1;
    int nE = T - base; if (nE > EB1) nE = EB1;
    for (int j = t; j < nE; j += 256) {
        int s, key;
        edge_at(base + j, src1, dst1, src2, dst2, E1, T1, E2, NR, s, key);
        atomicAdd(&cnt[key >> 9], 1u);
    }
    __syncthreads();
    for (int b = t; b < NB; b += 256) {
        u32 c = cnt[b];
        if (c) atomicAdd(&bucketCnt[b], c);
    }
}

// scanB: serial scan over NB buckets -> bucketBase, gcur; off[n2] = Etot
__global__ void kScanB(const u32* __restrict__ bucketCnt, int NB, int n2,
                       u32* __restrict__ bucketBase, u32* __restrict__ gcur,
                       int* __restrict__ off)
{
    if (threadIdx.x == 0) {
        u32 acc = 0;
        for (int b = 0; b < NB; b++) {
            bucketBase[b] = acc; gcur[b] = acc; acc += bucketCnt[b];
        }
        bucketBase[NB] = acc;
        off[n2] = (int)acc;
    }
}

// A2: local counting sort by bucket, contiguous run writes of packed (key,src)
__global__ __launch_bounds__(256) void kA2(const int* __restrict__ src1, const int* __restrict__ dst1,
    const int* __restrict__ src2, const int* __restrict__ dst2,
    int E1, int L1, int E2, int L2, int NR, int NB,
    u32* __restrict__ gcur, u64* __restrict__ pairs)
{
    __shared__ u64 ldsE[EB2];
    __shared__ u64 ldsS[EB2];
    __shared__ u32 cntA[512], cntB[512], offL[512], tmp[256];
    __shared__ u32 gbase[MAXNB];
    int t = threadIdx.x;
    for (int i = t; i < 512; i += 256) { cntA[i] = 0; cntB[i] = 0; }
    __syncthreads();
    int T1 = E1 + L1, T = T1 + E2 + L2;
    int base = blockIdx.x * EB2;
    int nE = T - base; if (nE > EB2) nE = EB2;
    for (int j = t; j < nE; j += 256) {
        int s, key;
        edge_at(base + j, src1, dst1, src2, dst2, E1, T1, E2, NR, s, key);
        ldsE[j] = ((u64)(u32)key << 32) | (u32)s;
        atomicAdd(&cntA[key >> 9], 1u);
    }
    __syncthreads();
    scan512(cntA, offL, tmp);
    for (int b = t; b < NB; b += 256) {
        u32 c = cntA[b];
        gbase[b] = c ? atomicAdd(&gcur[b], c) : 0u;
    }
    __syncthreads();
    for (int j = t; j < nE; j += 256) {
        u64 e = ldsE[j];
        u32 b = ((u32)(e >> 32)) >> 9;
        u32 r = atomicAdd(&cntB[b], 1u);
        ldsS[offL[b] + r] = e;
    }
    __syncthreads();
    for (int j = t; j < nE; j += 256) {
        u64 e = ldsS[j];
        u32 b = ((u32)(e >> 32)) >> 9;
        pairs[gbase[b] + ((u32)j - offL[b])] = e;
    }
}

// B: per-bucket fine sort -> off[] + sorted[] (sequential writes)
__global__ __launch_bounds__(256) void kB(const u64* __restrict__ pairs,
    const u32* __restrict__ bucketBase, int n2,
    int* __restrict__ off, int* __restrict__ sorted)
{
    __shared__ u32 cntA[512], cntB[512], offL[512], tmp[256];
    __shared__ u32 ldsS[8192];
    int b = blockIdx.x;
    int t = threadIdx.x;
    u32 beg = bucketBase[b], end = bucketBase[b + 1];
    int dstBase = b << 9;
    for (int i = t; i < 512; i += 256) { cntA[i] = 0; cntB[i] = 0; }
    __syncthreads();
    for (u32 j = beg + t; j < end; j += 256) {
        u32 key = (u32)(pairs[j] >> 32);
        atomicAdd(&cntA[key - dstBase], 1u);
    }
    __syncthreads();
    scan512(cntA, offL, tmp);
    for (int d = t; d < 512; d += 256) {
        int gk = dstBase + d;
        if (gk < n2) off[gk] = (int)(beg + offL[d]);
    }
    u32 cnt = end - beg;
    bool fast = cnt <= 8192u;
    __syncthreads();
    for (u32 j = beg + t; j < end; j += 256) {
        u64 e = pairs[j];
        u32 d = (u32)(e >> 32) - dstBase;
        u32 r = atomicAdd(&cntB[d], 1u);
        u32 pos = offL[d] + r;
        if (fast) ldsS[pos] = (u32)e;
        else sorted[beg + pos] = (int)(u32)e;
    }
    __syncthreads();
    if (fast) {
        for (u32 j = t; j < cnt; j += 256) sorted[beg + j] = (int)ldsS[j];
    }
}

// ---------------- GAT1 agg: 16B-per-edge psi aggregation (wave per dst) -----------
__global__ __launch_bounds__(256) void k_agg_lin(const int* __restrict__ off, const int* __restrict__ sorted,
    const float* __restrict__ a_s, const float* __restrict__ psi,
    const float* __restrict__ a_d, const float* __restrict__ advd,
    const float* __restrict__ cb, int NR, float* __restrict__ a_d_out)
{
    int wave = threadIdx.x >> 6, lane = threadIdx.x & 63;
    int d = blockIdx.x * 4 + wave;
    if (d >= NR) return;
    int beg = off[d], end = off[d + 1];
    float ad0 = a_d[d * 2 + 0], ad1 = a_d[d * 2 + 1];
    float w0s = 0.f, w1s = 0.f, a00 = 0.f, a01 = 0.f, a10 = 0.f, a11 = 0.f;
    for (int j = beg + lane; j < end; j += 64) {
        int s = sorted[j];
        float2 as = ((const float2*)a_s)[s];
        float e0 = as.x + ad0; e0 = (e0 >= 0.f) ? e0 : 0.2f * e0;
        float e1 = as.y + ad1; e1 = (e1 >= 0.f) ? e1 : 0.2f * e1;
        float x0 = __expf(e0), x1 = __expf(e1);
        float4 p = ((const float4*)psi)[s];
        w0s += x0; w1s += x1;
        a00 += x0 * p.x; a01 += x0 * p.y;
        a10 += x1 * p.z; a11 += x1 * p.w;
    }
    #pragma unroll
    for (int o = 32; o; o >>= 1) {
        w0s += __shfl_down(w0s, o); w1s += __shfl_down(w1s, o);
        a00 += __shfl_down(a00, o); a01 += __shfl_down(a01, o);
        a10 += __shfl_down(a10, o); a11 += __shfl_down(a11, o);
    }
    if (lane == 0) {
        float inv0 = 1.f / (w0s + 1e-16f), inv1 = 1.f / (w1s + 1e-16f);
        a_d_out[d * 2 + 0] = advd[d * 2 + 0] + cb[0] + 0.5f * (a00 * inv0 + a10 * inv1);
        a_d_out[d * 2 + 1] = advd[d * 2 + 1] + cb[1] + 0.5f * (a01 * inv0 + a11 * inv1);
    }
}

// ---------------- GAT2 agg: fused single-pass bf16 gather (wave per dst) ----------
__global__ __launch_bounds__(256) void k_agg_gather(const int* __restrict__ off, const int* __restrict__ sorted,
    const float* __restrict__ a_s, const float* __restrict__ a_d,
    const u16* __restrict__ hs16, const float* __restrict__ bias,
    int NR, float* __restrict__ out)
{
    int wave = threadIdx.x >> 6, lane = threadIdx.x & 63;
    int d = blockIdx.x * 4 + wave;
    if (d >= NR) return;
    int beg = off[d], end = off[d + 1];
    int slot = lane >> 5, head = (lane >> 4) & 1, cg = lane & 15;
    float adh = a_d[d * 2 + head];
    float wsum = 0.f;
    float acc[8];
    #pragma unroll
    for (int k = 0; k < 8; k++) acc[k] = 0.f;

    for (int base = beg; base < end; base += 64) {
        int rem = end - base; if (rem > 64) rem = 64;
        int pidx = base + ((lane < rem) ? lane : (rem - 1));
        int sp = sorted[pidx];
        float2 ap = ((const float2*)a_s)[sp];
        for (int i = 0; i < rem; i += 2) {
            int eo = i + slot;
            bool valid = eo < rem;
            int lsrc = valid ? eo : (rem - 1);
            int s   = __shfl(sp, lsrc);
            float asx = __shfl(ap.x, lsrc);
            float asy = __shfl(ap.y, lsrc);
            float as = head ? asy : asx;
            float ee = as + adh; ee = (ee >= 0.f) ? ee : 0.2f * ee;
            float w = valid ? __expf(ee) : 0.f;
            wsum += w;
            const u16* hrow = hs16 + (size_t)s * HC + (head << 7) + (cg << 3);
            uint4 g = *(const uint4*)hrow;
            acc[0] += w * bfbits2f(g.x & 0xFFFFu);
            acc[1] += w * __uint_as_float(g.x & 0xFFFF0000u);
            acc[2] += w * bfbits2f(g.y & 0xFFFFu);
            acc[3] += w * __uint_as_float(g.y & 0xFFFF0000u);
            acc[4] += w * bfbits2f(g.z & 0xFFFFu);
            acc[5] += w * __uint_as_float(g.z & 0xFFFF0000u);
            acc[6] += w * bfbits2f(g.w & 0xFFFFu);
            acc[7] += w * __uint_as_float(g.w & 0xFFFF0000u);
        }
    }
    wsum += __shfl(wsum, lane ^ 32);
    #pragma unroll
    for (int k = 0; k < 8; k++) acc[k] += __shfl(acc[k], lane ^ 32);
    float inv = 1.f / (wsum + 1e-16f);
    #pragma unroll
    for (int k = 0; k < 8; k++) acc[k] *= inv;
    #pragma unroll
    for (int k = 0; k < 8; k++) acc[k] = 0.5f * (acc[k] + __shfl(acc[k], lane ^ 16));
    if (lane < 16) {
        const float4* b4 = (const float4*)bias;
        float4 bb0 = b4[cg * 2], bb1 = b4[cg * 2 + 1];
        float4 o0, o1;
        o0.x = acc[0] + bb0.x; o0.y = acc[1] + bb0.y; o0.z = acc[2] + bb0.z; o0.w = acc[3] + bb0.w;
        o1.x = acc[4] + bb1.x; o1.y = acc[5] + bb1.y; o1.z = acc[6] + bb1.z; o1.w = acc[7] + bb1.w;
        float4* op = (float4*)(out + (size_t)d * C + (cg << 3));
        op[0] = o0; op[1] = o1;
    }
}

extern "C" void kernel_launch(void* const* d_in, const int* in_sizes, int n_in,
                              void* d_out, int out_size, void* d_ws, size_t ws_size,
                              hipStream_t stream) {
    const int*   user_ids       = (const int*)d_in[0];
    const int*   ingredient_ids = (const int*)d_in[1];
    const float* recipe_x       = (const float*)d_in[2];
    const int*   ing_src        = (const int*)d_in[3];
    const int*   ing_dst        = (const int*)d_in[4];
    const int*   ub_src         = (const int*)d_in[5];
    const int*   ub_dst         = (const int*)d_in[6];
    const float* user_table     = (const float*)d_in[7];
    const float* ing_table      = (const float*)d_in[8];
    const float* W_rl           = (const float*)d_in[9];
    const float* bn_gamma       = (const float*)d_in[11];
    const float* bn_beta        = (const float*)d_in[12];
    const float* g1_ws          = (const float*)d_in[13];
    const float* g1_wd          = (const float*)d_in[14];
    const float* g1_as          = (const float*)d_in[15];
    const float* g1_ad          = (const float*)d_in[16];
    const float* g1_b           = (const float*)d_in[17];
    const float* g2_ws          = (const float*)d_in[18];
    const float* g2_wd          = (const float*)d_in[19];
    const float* g2_as          = (const float*)d_in[20];
    const float* g2_ad          = (const float*)d_in[21];
    const float* g2_b           = (const float*)d_in[22];

    int NU = in_sizes[0];
    int NI = in_sizes[1];
    int NR = in_sizes[2] / DIN;
    int E1 = in_sizes[3];
    int E2 = in_sizes[5];
    int Nmax = (NI > NU) ? NI : NU;
    int L1 = (NI < NR) ? NI : NR;
    int L2 = (NU < NR) ? NU : NR;
    int Etot = E1 + L1 + E2 + L2;
    int n2 = 2 * NR;
    int NB = (n2 + 511) >> 9;

    char* w = (char*)d_ws;
    u16*   hs16  = (u16*)w;    w += (size_t)Nmax * HC * 2;
    float* a_s   = (float*)w;  w += (size_t)Nmax * 2 * 4;
    float* psi   = (float*)w;  w += (size_t)NI * 4 * 4;
    float* a_d   = (float*)w;  w += (size_t)NR * 2 * 4;
    float* advd  = (float*)w;  w += (size_t)NR * 2 * 4;
    float* stats = (float*)w;  w += 2304 * 4;
    u16*   wsp   = (u16*)w;    w += 32768 * 2;
    u32*   bucketCnt  = (u32*)w; w += MAXNB * 4;
    u32*   bucketBase = (u32*)w; w += (MAXNB + 1) * 4;
    u32*   gcur  = (u32*)w;    w += MAXNB * 4;
    int*   off   = (int*)w;    w += (size_t)(n2 + 1) * 4;
    int*   sorted= (int*)w;    w += (size_t)Etot * 4;
    w = (char*)(((size_t)w + 15) & ~(size_t)15);
    u64*   pairs = (u64*)w;    w += (size_t)Etot * 8;

    hipMemsetAsync(stats, 0, 420 * 4, stream);
    hipMemsetAsync(bucketCnt, 0, MAXNB * 4, stream);

    // BN stats + folded constants + B-pack
    k_stats<<<(NR + 255) / 256, 256, 0, stream>>>(recipe_x, NR, stats);
    k_precomp<<<1, 256, 0, stream>>>(stats, W_rl, bn_gamma, bn_beta,
                                     g1_wd, g1_ad, g2_wd, g2_ad,
                                     g1_ws, g1_as, g2_ws, g2_as, g1_b, 1.0f / NR);
    k_pack<<<32, 256, 0, stream>>>(g2_ws, wsp);
    // bucketed CSR build (both graphs, key space 2*NR)
    kA1<<<(Etot + EB1 - 1) / EB1, 256, 0, stream>>>(ing_src, ing_dst, ub_src, ub_dst,
                                                    E1, L1, E2, L2, NR, NB, bucketCnt);
    kScanB<<<1, 64, 0, stream>>>(bucketCnt, NB, n2, bucketBase, gcur, off);
    kA2<<<(Etot + EB2 - 1) / EB2, 256, 0, stream>>>(ing_src, ing_dst, ub_src, ub_dst,
                                                    E1, L1, E2, L2, NR, NB, gcur, pairs);
    kB<<<NB, 256, 0, stream>>>(pairs, bucketBase, n2, off, sorted);
    // GAT1: psi-based, no GEMM
    k_r0<<<(NR + 15) / 16, 256, 0, stream>>>(recipe_x, W_rl, stats, NR, a_d, advd);
    k_ing<<<(NI + 31) / 32, 256, 0, stream>>>(ing_table, ingredient_ids, stats, NI, a_s, psi);
    k_agg_lin<<<(NR + 3) / 4, 256, 0, stream>>>(off, sorted, a_s, psi, a_d, advd,
                                                stats + 1188, NR, a_d);
    // GAT2: MFMA hs GEMM + bf16 gather
    k_hs_mfma<<<(NU + 31) / 32, 256, 0, stream>>>(user_table, user_ids, wsp, stats, NU,
                                                  hs16, a_s);
    k_agg_gather<<<(NR + 3) / 4, 256, 0, stream>>>(off + NR, sorted, a_s, a_d, hs16,
                                                   g2_b, NR, (float*)d_out);
}